// Round 3
// baseline (405.543 us; speedup 1.0000x reference)
//
#include <hip/hip_runtime.h>
#include <hip/hip_bf16.h>
#include <math.h>

// ---------------------------------------------------------------------------
// GCN 2-layer forward on MI355X.
// memset counts -> hist(dst) -> 3-phase scan -> fill_csr
//   -> gemm1 (x fp32 @ W1, *dinv, out bf16)
//   -> agg1  (bf16 gather, fp32 acc, +b1, relu, out bf16)
//   -> gemm2 (bf16 in, fp32 LDS, *dinv, out fp32)
//   -> agg2  (fp32 gather, +b2, log_softmax)
// dinv folded into GEMM epilogue: hs[n] = (X@W)[n]*dinv[n];
//   out[n] = dn*(hs[n] + sum_nbr hs[s]) + b.
// h1/h1a stored bf16 (gather tables halve -> L2-miss path traffic halves).
// ---------------------------------------------------------------------------

typedef unsigned int uint32;

__device__ inline unsigned short f2bf_rne(float f) {
    uint32 x = __float_as_uint(f);
    uint32 r = (x + 0x7fffu + ((x >> 16) & 1u)) >> 16;
    return (unsigned short)r;
}
__device__ inline uint32 pack_bf16x2(float a, float b) {
    return (uint32)f2bf_rne(a) | ((uint32)f2bf_rne(b) << 16);
}
__device__ inline float2 unpack_bf16x2(uint32 u) {
    float2 r;
    r.x = __uint_as_float(u << 16);
    r.y = __uint_as_float(u & 0xffff0000u);
    return r;
}

__global__ void hist_k(const int* __restrict__ dst, int E, int* __restrict__ counts) {
    int e = blockIdx.x * blockDim.x + threadIdx.x;
    if (e < E) atomicAdd(&counts[dst[e]], 1);
}

__global__ __launch_bounds__(256) void partial_scan_k(const int* __restrict__ counts, int N,
                                                      int* __restrict__ exscan,
                                                      int* __restrict__ blocksum,
                                                      float* __restrict__ dinv) {
    __shared__ int sd[256];
    const int tid = threadIdx.x;
    const int gid = blockIdx.x * 256 + tid;
    int v = (gid < N) ? counts[gid] : 0;
    sd[tid] = v;
    __syncthreads();
    for (int off = 1; off < 256; off <<= 1) {
        int t = (tid >= off) ? sd[tid - off] : 0;
        __syncthreads();
        sd[tid] += t;
        __syncthreads();
    }
    if (gid < N) {
        exscan[gid] = sd[tid] - v;
        dinv[gid]   = rsqrtf((float)(v + 1));
    }
    if (tid == 255) blocksum[blockIdx.x] = sd[255];
}

__global__ __launch_bounds__(256) void scan_blocksums_k(const int* __restrict__ blocksum, int NB,
                                                        int* __restrict__ blockoff,
                                                        int* __restrict__ offsets_last) {
    __shared__ int sd[256];
    const int tid = threadIdx.x;
    int v = (tid < NB) ? blocksum[tid] : 0;
    sd[tid] = v;
    __syncthreads();
    for (int off = 1; off < 256; off <<= 1) {
        int t = (tid >= off) ? sd[tid - off] : 0;
        __syncthreads();
        sd[tid] += t;
        __syncthreads();
    }
    if (tid < NB) blockoff[tid] = sd[tid] - v;
    if (tid == 255) *offsets_last = sd[255];
}

__global__ __launch_bounds__(256) void finalize_k(const int* __restrict__ exscan,
                                                  const int* __restrict__ blockoff, int N,
                                                  int* __restrict__ offsets,
                                                  int* __restrict__ cursor) {
    const int gid = blockIdx.x * 256 + threadIdx.x;
    if (gid < N) {
        int o = blockoff[blockIdx.x] + exscan[gid];
        offsets[gid] = o;
        cursor[gid]  = o;
    }
}

__global__ void fill_csr_k(const int* __restrict__ src, const int* __restrict__ dst, int E,
                           int* __restrict__ cursor, int* __restrict__ csr_src) {
    int e = blockIdx.x * blockDim.x + threadIdx.x;
    if (e < E) {
        int pos = atomicAdd(&cursor[dst[e]], 1);
        csr_src[pos] = src[e];
    }
}

// fp32-math GEMM Y[r,:] = (X[r,:] @ W) * dinv[r].
// XBF: X stored bf16 (unpack during LDS staging). YBF: store Y as bf16.
template <int NCOL, int MT, bool XBF, bool YBF>
__global__ __launch_bounds__(256) void gemm_k(const void* __restrict__ Xv,
                                              const float* __restrict__ W,
                                              const float* __restrict__ dinv,
                                              void* __restrict__ Yv, int Nrows) {
    constexpr int K  = 128;
    constexpr int KB = 64;
    constexpr int CG = NCOL / 4;
    __shared__ float Wl[KB * NCOL];
    __shared__ float Xl[MT * K];
    const int tid = threadIdx.x;
    const int r0  = blockIdx.x * MT;

    if (XBF) {
        // bf16 X: read uint2 (4 vals), unpack, float4 -> LDS
        const uint2* Xg = (const uint2*)Xv;  // row stride K/4 uint2
        for (int i = tid; i < MT * (K / 4); i += 256) {
            int row = i >> 5;  // K/4 == 32
            int g   = i & 31;
            float4 v = {0.f, 0.f, 0.f, 0.f};
            if (r0 + row < Nrows) {
                uint2 u = Xg[(size_t)(r0 + row) * 32 + g];
                float2 a = unpack_bf16x2(u.x);
                float2 b = unpack_bf16x2(u.y);
                v = make_float4(a.x, a.y, b.x, b.y);
            }
            *(float4*)&Xl[row * K + 4 * g] = v;
        }
    } else {
        const float4* Xg = (const float4*)Xv;
        float4* Xl4 = (float4*)Xl;
        for (int i = tid; i < MT * (K / 4); i += 256) {
            int row = i >> 5;
            float4 v = {0.f, 0.f, 0.f, 0.f};
            if (r0 + row < Nrows) v = Xg[(size_t)(r0 + row) * 32 + (i & 31)];
            Xl4[i] = v;
        }
    }

    const int cg = tid % CG;
    const int rg = tid / CG;
    alignas(16) float acc[4][4];
#pragma unroll
    for (int i = 0; i < 4; ++i)
#pragma unroll
        for (int c = 0; c < 4; ++c) acc[i][c] = 0.f;

    float4* Wl4 = (float4*)Wl;
    const float4* Wg4 = (const float4*)W;
    for (int kb = 0; kb < K; kb += KB) {
        __syncthreads();
        for (int i = tid; i < KB * (NCOL / 4); i += 256)
            Wl4[i] = Wg4[kb * (NCOL / 4) + i];
        __syncthreads();
        for (int k = 0; k < KB; k += 4) {
            alignas(16) float w4[4][4];
            alignas(16) float x4[4][4];
#pragma unroll
            for (int j = 0; j < 4; ++j)
                *(float4*)&w4[j][0] = *(const float4*)&Wl[(k + j) * NCOL + 4 * cg];
#pragma unroll
            for (int i = 0; i < 4; ++i)
                *(float4*)&x4[i][0] = *(const float4*)&Xl[(4 * rg + i) * K + kb + k];
#pragma unroll
            for (int i = 0; i < 4; ++i)
#pragma unroll
                for (int c = 0; c < 4; ++c)
                    acc[i][c] += x4[i][0] * w4[0][c] + x4[i][1] * w4[1][c] +
                                 x4[i][2] * w4[2][c] + x4[i][3] * w4[3][c];
        }
    }
#pragma unroll
    for (int i = 0; i < 4; ++i) {
        int row = r0 + 4 * rg + i;
        if (row < Nrows) {
            float dn = dinv[row];
            if (YBF) {
                unsigned short* Yb = (unsigned short*)Yv;
                uint2 o;
                o.x = pack_bf16x2(acc[i][0] * dn, acc[i][1] * dn);
                o.y = pack_bf16x2(acc[i][2] * dn, acc[i][3] * dn);
                *(uint2*)&Yb[(size_t)row * NCOL + 4 * cg] = o;
            } else {
                float* Yf = (float*)Yv;
                float4 o = {acc[i][0] * dn, acc[i][1] * dn, acc[i][2] * dn, acc[i][3] * dn};
                *(float4*)&Yf[(size_t)row * NCOL + 4 * cg] = o;
            }
        }
    }
}

// Layer-1 aggregation on bf16 table: 64 lanes/node, 2 ch/lane (packed uint),
// 4 nodes per 256-thread block. out = relu(dn*(self + sum nbr) + b1), bf16 out.
__global__ __launch_bounds__(256) void agg1_k(const unsigned short* __restrict__ hs,
                                              const int* __restrict__ offsets,
                                              const int* __restrict__ csr_src,
                                              const float* __restrict__ dinv,
                                              const float* __restrict__ b1,
                                              unsigned short* __restrict__ out, int N) {
    const int tid  = threadIdx.x;
    const int node = blockIdx.x * 4 + (tid >> 6);
    const int lane = tid & 63;  // 2 channels: 2*lane, 2*lane+1
    if (node >= N) return;
    const uint32* T = (const uint32*)hs;  // row stride 64 uints
    const int start = offsets[node];
    const int end   = offsets[node + 1];
    const float dn  = dinv[node];
    float2 self = unpack_bf16x2(T[(size_t)node * 64 + lane]);
    float ax0 = self.x, ay0 = self.y, ax1 = 0.f, ay1 = 0.f;
    int p = start;
    for (; p + 1 < end; p += 2) {
        int s0 = csr_src[p];
        int s1 = csr_src[p + 1];
        float2 f0 = unpack_bf16x2(T[(size_t)s0 * 64 + lane]);
        float2 f1 = unpack_bf16x2(T[(size_t)s1 * 64 + lane]);
        ax0 += f0.x; ay0 += f0.y;
        ax1 += f1.x; ay1 += f1.y;
    }
    if (p < end) {
        float2 f = unpack_bf16x2(T[(size_t)csr_src[p] * 64 + lane]);
        ax1 += f.x; ay1 += f.y;
    }
    float2 bb = ((const float2*)b1)[lane];
    float vx = (ax0 + ax1) * dn + bb.x;
    float vy = (ay0 + ay1) * dn + bb.y;
    vx = vx > 0.f ? vx : 0.f;
    vy = vy > 0.f ? vy : 0.f;
    ((uint32*)out)[(size_t)node * 64 + lane] = pack_bf16x2(vx, vy);
}

// Layer-2 aggregation + bias + log_softmax (fp32 table). One wave per node.
__global__ __launch_bounds__(256) void agg2_k(const float* __restrict__ hs,
                                              const int* __restrict__ offsets,
                                              const int* __restrict__ csr_src,
                                              const float* __restrict__ dinv,
                                              const float* __restrict__ b2,
                                              float* __restrict__ out, int N) {
    const int tid  = threadIdx.x;
    const int node = blockIdx.x * 4 + (tid >> 6);
    const int ch   = tid & 63;
    if (node >= N) return;
    const int start = offsets[node];
    const int end   = offsets[node + 1];
    const float dn  = dinv[node];
    float acc0 = hs[(size_t)node * 64 + ch];
    float acc1 = 0.f;
    int p = start;
    for (; p + 1 < end; p += 2) {
        int s0 = csr_src[p];
        int s1 = csr_src[p + 1];
        acc0 += hs[(size_t)s0 * 64 + ch];
        acc1 += hs[(size_t)s1 * 64 + ch];
    }
    if (p < end) acc1 += hs[(size_t)csr_src[p] * 64 + ch];
    float v = (acc0 + acc1) * dn + b2[ch];
    float m = v;
#pragma unroll
    for (int off = 32; off > 0; off >>= 1) m = fmaxf(m, __shfl_xor(m, off, 64));
    float ex = __expf(v - m);
    float ssum = ex;
#pragma unroll
    for (int off = 32; off > 0; off >>= 1) ssum += __shfl_xor(ssum, off, 64);
    out[(size_t)node * 64 + ch] = v - m - __logf(ssum);
}

extern "C" void kernel_launch(void* const* d_in, const int* in_sizes, int n_in,
                              void* d_out, int out_size, void* d_ws, size_t ws_size,
                              hipStream_t stream) {
    const float* x  = (const float*)d_in[0];
    const int*   ei = (const int*)d_in[1];
    const float* W1 = (const float*)d_in[2];
    const float* b1 = (const float*)d_in[3];
    const float* W2 = (const float*)d_in[4];
    const float* b2 = (const float*)d_in[5];
    float* out = (float*)d_out;

    const int N = in_sizes[0] / 128;  // 50000
    const int E = in_sizes[1] / 2;    // 800000
    const int* src = ei;
    const int* dst = ei + E;
    const int NB = (N + 255) / 256;

    char* ws = (char*)d_ws;
    auto alloc = [&](size_t bytes) -> char* {
        char* p = ws;
        ws += (bytes + 255) & ~(size_t)255;
        return p;
    };
    unsigned short* h1  = (unsigned short*)alloc((size_t)N * 128 * 2);  // bf16
    unsigned short* h1a = (unsigned short*)alloc((size_t)N * 128 * 2);  // bf16
    float* h2       = (float*)alloc((size_t)N * 64 * 4);
    float* dinv     = (float*)alloc((size_t)N * 4);
    int*   counts   = (int*)alloc((size_t)N * 4);
    int*   exscan   = (int*)alloc((size_t)N * 4);
    int*   blocksum = (int*)alloc((size_t)NB * 4);
    int*   blockoff = (int*)alloc((size_t)NB * 4);
    int*   offsets  = (int*)alloc((size_t)(N + 1) * 4);
    int*   cursor   = (int*)alloc((size_t)N * 4);
    int*   csr_src  = (int*)alloc((size_t)E * 4);

    hipMemsetAsync(counts, 0, (size_t)N * 4, stream);
    hist_k<<<(E + 255) / 256, 256, 0, stream>>>(dst, E, counts);
    partial_scan_k<<<NB, 256, 0, stream>>>(counts, N, exscan, blocksum, dinv);
    scan_blocksums_k<<<1, 256, 0, stream>>>(blocksum, NB, blockoff, offsets + N);
    finalize_k<<<NB, 256, 0, stream>>>(exscan, blockoff, N, offsets, cursor);
    fill_csr_k<<<(E + 255) / 256, 256, 0, stream>>>(src, dst, E, cursor, csr_src);

    gemm_k<128, 32, false, true><<<(N + 31) / 32, 256, 0, stream>>>(x, W1, dinv, h1, N);
    agg1_k<<<(N + 3) / 4, 256, 0, stream>>>(h1, offsets, csr_src, dinv, b1, h1a, N);
    gemm_k<64, 64, true, false><<<(N + 63) / 64, 256, 0, stream>>>(h1a, W2, dinv, h2, N);
    agg2_k<<<(N + 3) / 4, 256, 0, stream>>>(h2, offsets, csr_src, dinv, b2, out, N);
}

// Round 4
// 307.144 us; speedup vs baseline: 1.3204x; 1.3204x over previous
//
#include <hip/hip_runtime.h>
#include <hip/hip_bf16.h>
#include <math.h>

// ---------------------------------------------------------------------------
// GCN 2-layer forward on MI355X.
// memset counts -> hist(dst) -> 3-phase scan -> fill_csr -> convw (W->bf16^T)
//   -> mfma_gemm1 (x fp32->bf16 frags @ W1t, *dinv, out bf16 h1)
//   -> agg1  (bf16 gather, fp32 acc, +b1, relu, out bf16 h1a)
//   -> mfma_gemm2 (h1a bf16 @ W2t, *dinv, out fp32 h2)
//   -> agg2  (fp32 gather, +b2, log_softmax)
// dinv folded into GEMM epilogue: hs[n] = (X@W)[n]*dinv[n];
//   out[n] = dn*(hs[n] + sum_nbr hs[s]) + b.
// MFMA fragment layouts (gfx950, learn_hip-verified):
//   A: A[m=lane&15][k=(lane>>4)*8+j]  (8 bf16 = one 16B load)
//   B: B[k=(lane>>4)*8+j][n=lane&15]  (contiguous if W stored transposed)
//   C/D: col=lane&15, row=(lane>>4)*4+reg
// ---------------------------------------------------------------------------

typedef unsigned int uint32;
typedef __attribute__((ext_vector_type(8))) short bf16x8;
typedef __attribute__((ext_vector_type(4))) float f32x4;

__device__ inline unsigned short f2bf_rne(float f) {
    uint32 x = __float_as_uint(f);
    uint32 r = (x + 0x7fffu + ((x >> 16) & 1u)) >> 16;
    return (unsigned short)r;
}
__device__ inline uint32 pack_bf16x2(float a, float b) {
    return (uint32)f2bf_rne(a) | ((uint32)f2bf_rne(b) << 16);
}
__device__ inline float2 unpack_bf16x2(uint32 u) {
    float2 r;
    r.x = __uint_as_float(u << 16);
    r.y = __uint_as_float(u & 0xffff0000u);
    return r;
}

__global__ void hist_k(const int* __restrict__ dst, int E, int* __restrict__ counts) {
    int e = blockIdx.x * blockDim.x + threadIdx.x;
    if (e < E) atomicAdd(&counts[dst[e]], 1);
}

__global__ __launch_bounds__(256) void partial_scan_k(const int* __restrict__ counts, int N,
                                                      int* __restrict__ exscan,
                                                      int* __restrict__ blocksum,
                                                      float* __restrict__ dinv) {
    __shared__ int sd[256];
    const int tid = threadIdx.x;
    const int gid = blockIdx.x * 256 + tid;
    int v = (gid < N) ? counts[gid] : 0;
    sd[tid] = v;
    __syncthreads();
    for (int off = 1; off < 256; off <<= 1) {
        int t = (tid >= off) ? sd[tid - off] : 0;
        __syncthreads();
        sd[tid] += t;
        __syncthreads();
    }
    if (gid < N) {
        exscan[gid] = sd[tid] - v;
        dinv[gid]   = rsqrtf((float)(v + 1));
    }
    if (tid == 255) blocksum[blockIdx.x] = sd[255];
}

__global__ __launch_bounds__(256) void scan_blocksums_k(const int* __restrict__ blocksum, int NB,
                                                        int* __restrict__ blockoff,
                                                        int* __restrict__ offsets_last) {
    __shared__ int sd[256];
    const int tid = threadIdx.x;
    int v = (tid < NB) ? blocksum[tid] : 0;
    sd[tid] = v;
    __syncthreads();
    for (int off = 1; off < 256; off <<= 1) {
        int t = (tid >= off) ? sd[tid - off] : 0;
        __syncthreads();
        sd[tid] += t;
        __syncthreads();
    }
    if (tid < NB) blockoff[tid] = sd[tid] - v;
    if (tid == 255) *offsets_last = sd[255];
}

__global__ __launch_bounds__(256) void finalize_k(const int* __restrict__ exscan,
                                                  const int* __restrict__ blockoff, int N,
                                                  int* __restrict__ offsets,
                                                  int* __restrict__ cursor) {
    const int gid = blockIdx.x * 256 + threadIdx.x;
    if (gid < N) {
        int o = blockoff[blockIdx.x] + exscan[gid];
        offsets[gid] = o;
        cursor[gid]  = o;
    }
}

__global__ void fill_csr_k(const int* __restrict__ src, const int* __restrict__ dst, int E,
                           int* __restrict__ cursor, int* __restrict__ csr_src) {
    int e = blockIdx.x * blockDim.x + threadIdx.x;
    if (e < E) {
        int pos = atomicAdd(&cursor[dst[e]], 1);
        csr_src[pos] = src[e];
    }
}

// W1 [128][128] and W2 [128][64] fp32 row-major -> bf16 transposed [n][k].
__global__ __launch_bounds__(256) void convw_k(const float* __restrict__ W1,
                                               const float* __restrict__ W2,
                                               unsigned short* __restrict__ W1t,
                                               unsigned short* __restrict__ W2t) {
    int idx = blockIdx.x * 256 + threadIdx.x;
    if (idx < 128 * 128) {
        int n = idx >> 7, k = idx & 127;
        W1t[idx] = f2bf_rne(W1[k * 128 + n]);
    } else {
        int i2 = idx - 128 * 128;
        if (i2 < 64 * 128) {
            int n = i2 >> 7, k = i2 & 127;
            W2t[i2] = f2bf_rne(W2[k * 64 + n]);
        }
    }
}

// MFMA GEMM: Y[r,:] = (X[r,:128] @ W) * dinv[r].
// Wt: [NCOL][128] bf16 transposed. Block = 4 waves, wave = 16 rows x NCOL.
// ABF: X is bf16 (else fp32, converted in-register). YBF: Y stored bf16.
template <int NCOL, bool ABF, bool YBF>
__global__ __launch_bounds__(256) void mfma_gemm_k(const void* __restrict__ Xv,
                                                   const unsigned short* __restrict__ Wt,
                                                   const float* __restrict__ dinv,
                                                   void* __restrict__ Yv, int Nrows) {
    constexpr int NT = NCOL / 16;  // n-tiles per wave
    const int tid  = threadIdx.x;
    const int wave = tid >> 6;
    const int lane = tid & 63;
    const int m16  = lane & 15;
    const int q    = lane >> 4;
    const int r0   = blockIdx.x * 64 + wave * 16;

    int arow = r0 + m16;
    if (arow >= Nrows) arow = Nrows - 1;

    bf16x8 afrag[4];
    if (ABF) {
        const unsigned short* X = (const unsigned short*)Xv;
#pragma unroll
        for (int kb = 0; kb < 4; ++kb)
            afrag[kb] = *(const bf16x8*)&X[(size_t)arow * 128 + kb * 32 + q * 8];
    } else {
        const float* X = (const float*)Xv;
#pragma unroll
        for (int kb = 0; kb < 4; ++kb) {
            const float* p = &X[(size_t)arow * 128 + kb * 32 + q * 8];
            float4 u0 = *(const float4*)p;
            float4 u1 = *(const float4*)(p + 4);
            bf16x8 a;
            a[0] = (short)f2bf_rne(u0.x); a[1] = (short)f2bf_rne(u0.y);
            a[2] = (short)f2bf_rne(u0.z); a[3] = (short)f2bf_rne(u0.w);
            a[4] = (short)f2bf_rne(u1.x); a[5] = (short)f2bf_rne(u1.y);
            a[6] = (short)f2bf_rne(u1.z); a[7] = (short)f2bf_rne(u1.w);
            afrag[kb] = a;
        }
    }

    f32x4 acc[NT];
#pragma unroll
    for (int t = 0; t < NT; ++t) acc[t] = (f32x4){0.f, 0.f, 0.f, 0.f};

#pragma unroll
    for (int t = 0; t < NT; ++t) {
        const unsigned short* Bp = &Wt[(size_t)(t * 16 + m16) * 128 + q * 8];
#pragma unroll
        for (int kb = 0; kb < 4; ++kb) {
            bf16x8 bfrag = *(const bf16x8*)&Bp[kb * 32];
            acc[t] = __builtin_amdgcn_mfma_f32_16x16x32_bf16(afrag[kb], bfrag, acc[t], 0, 0, 0);
        }
    }

#pragma unroll
    for (int i = 0; i < 4; ++i) {
        int row = r0 + q * 4 + i;
        if (row < Nrows) {
            float dn = dinv[row];
#pragma unroll
            for (int t = 0; t < NT; ++t) {
                float v = acc[t][i] * dn;
                int col = t * 16 + m16;
                if (YBF)
                    ((unsigned short*)Yv)[(size_t)row * NCOL + col] = f2bf_rne(v);
                else
                    ((float*)Yv)[(size_t)row * NCOL + col] = v;
            }
        }
    }
}

// Layer-1 aggregation on bf16 table: 64 lanes/node, 2 ch/lane (packed uint),
// 4 nodes per 256-thread block. out = relu(dn*(self + sum nbr) + b1), bf16 out.
__global__ __launch_bounds__(256) void agg1_k(const unsigned short* __restrict__ hs,
                                              const int* __restrict__ offsets,
                                              const int* __restrict__ csr_src,
                                              const float* __restrict__ dinv,
                                              const float* __restrict__ b1,
                                              unsigned short* __restrict__ out, int N) {
    const int tid  = threadIdx.x;
    const int node = blockIdx.x * 4 + (tid >> 6);
    const int lane = tid & 63;
    if (node >= N) return;
    const uint32* T = (const uint32*)hs;
    const int start = offsets[node];
    const int end   = offsets[node + 1];
    const float dn  = dinv[node];
    float2 self = unpack_bf16x2(T[(size_t)node * 64 + lane]);
    float ax0 = self.x, ay0 = self.y, ax1 = 0.f, ay1 = 0.f;
    int p = start;
    for (; p + 1 < end; p += 2) {
        int s0 = csr_src[p];
        int s1 = csr_src[p + 1];
        float2 f0 = unpack_bf16x2(T[(size_t)s0 * 64 + lane]);
        float2 f1 = unpack_bf16x2(T[(size_t)s1 * 64 + lane]);
        ax0 += f0.x; ay0 += f0.y;
        ax1 += f1.x; ay1 += f1.y;
    }
    if (p < end) {
        float2 f = unpack_bf16x2(T[(size_t)csr_src[p] * 64 + lane]);
        ax1 += f.x; ay1 += f.y;
    }
    float2 bb = ((const float2*)b1)[lane];
    float vx = (ax0 + ax1) * dn + bb.x;
    float vy = (ay0 + ay1) * dn + bb.y;
    vx = vx > 0.f ? vx : 0.f;
    vy = vy > 0.f ? vy : 0.f;
    ((uint32*)out)[(size_t)node * 64 + lane] = pack_bf16x2(vx, vy);
}

// Layer-2 aggregation + bias + log_softmax (fp32 table). One wave per node.
__global__ __launch_bounds__(256) void agg2_k(const float* __restrict__ hs,
                                              const int* __restrict__ offsets,
                                              const int* __restrict__ csr_src,
                                              const float* __restrict__ dinv,
                                              const float* __restrict__ b2,
                                              float* __restrict__ out, int N) {
    const int tid  = threadIdx.x;
    const int node = blockIdx.x * 4 + (tid >> 6);
    const int ch   = tid & 63;
    if (node >= N) return;
    const int start = offsets[node];
    const int end   = offsets[node + 1];
    const float dn  = dinv[node];
    float acc0 = hs[(size_t)node * 64 + ch];
    float acc1 = 0.f;
    int p = start;
    for (; p + 1 < end; p += 2) {
        int s0 = csr_src[p];
        int s1 = csr_src[p + 1];
        acc0 += hs[(size_t)s0 * 64 + ch];
        acc1 += hs[(size_t)s1 * 64 + ch];
    }
    if (p < end) acc1 += hs[(size_t)csr_src[p] * 64 + ch];
    float v = (acc0 + acc1) * dn + b2[ch];
    float m = v;
#pragma unroll
    for (int off = 32; off > 0; off >>= 1) m = fmaxf(m, __shfl_xor(m, off, 64));
    float ex = __expf(v - m);
    float ssum = ex;
#pragma unroll
    for (int off = 32; off > 0; off >>= 1) ssum += __shfl_xor(ssum, off, 64);
    out[(size_t)node * 64 + ch] = v - m - __logf(ssum);
}

extern "C" void kernel_launch(void* const* d_in, const int* in_sizes, int n_in,
                              void* d_out, int out_size, void* d_ws, size_t ws_size,
                              hipStream_t stream) {
    const float* x  = (const float*)d_in[0];
    const int*   ei = (const int*)d_in[1];
    const float* W1 = (const float*)d_in[2];
    const float* b1 = (const float*)d_in[3];
    const float* W2 = (const float*)d_in[4];
    const float* b2 = (const float*)d_in[5];
    float* out = (float*)d_out;

    const int N = in_sizes[0] / 128;  // 50000
    const int E = in_sizes[1] / 2;    // 800000
    const int* src = ei;
    const int* dst = ei + E;
    const int NB = (N + 255) / 256;

    char* ws = (char*)d_ws;
    auto alloc = [&](size_t bytes) -> char* {
        char* p = ws;
        ws += (bytes + 255) & ~(size_t)255;
        return p;
    };
    unsigned short* h1  = (unsigned short*)alloc((size_t)N * 128 * 2);  // bf16
    unsigned short* h1a = (unsigned short*)alloc((size_t)N * 128 * 2);  // bf16
    float* h2       = (float*)alloc((size_t)N * 64 * 4);
    float* dinv     = (float*)alloc((size_t)N * 4);
    int*   counts   = (int*)alloc((size_t)N * 4);
    int*   exscan   = (int*)alloc((size_t)N * 4);
    int*   blocksum = (int*)alloc((size_t)NB * 4);
    int*   blockoff = (int*)alloc((size_t)NB * 4);
    int*   offsets  = (int*)alloc((size_t)(N + 1) * 4);
    int*   cursor   = (int*)alloc((size_t)N * 4);
    int*   csr_src  = (int*)alloc((size_t)E * 4);
    unsigned short* W1t = (unsigned short*)alloc(128 * 128 * 2);
    unsigned short* W2t = (unsigned short*)alloc(64 * 128 * 2);

    hipMemsetAsync(counts, 0, (size_t)N * 4, stream);
    hist_k<<<(E + 255) / 256, 256, 0, stream>>>(dst, E, counts);
    partial_scan_k<<<NB, 256, 0, stream>>>(counts, N, exscan, blocksum, dinv);
    scan_blocksums_k<<<1, 256, 0, stream>>>(blocksum, NB, blockoff, offsets + N);
    finalize_k<<<NB, 256, 0, stream>>>(exscan, blockoff, N, offsets, cursor);
    fill_csr_k<<<(E + 255) / 256, 256, 0, stream>>>(src, dst, E, cursor, csr_src);
    convw_k<<<(128 * 128 + 64 * 128 + 255) / 256, 256, 0, stream>>>(W1, W2, W1t, W2t);

    const int GB = (N + 63) / 64;  // 782 gemm blocks
    mfma_gemm_k<128, false, true><<<GB, 256, 0, stream>>>(x, W1t, dinv, h1, N);
    agg1_k<<<(N + 3) / 4, 256, 0, stream>>>(h1, offsets, csr_src, dinv, b1, h1a, N);
    mfma_gemm_k<64, true, false><<<GB, 256, 0, stream>>>(h1a, W2t, dinv, h2, N);
    agg2_k<<<(N + 3) / 4, 256, 0, stream>>>(h2, offsets, csr_src, dinv, b2, out, N);
}

// Round 5
// 275.024 us; speedup vs baseline: 1.4746x; 1.1168x over previous
//
#include <hip/hip_runtime.h>
#include <hip/hip_bf16.h>
#include <math.h>

// ---------------------------------------------------------------------------
// GCN 2-layer forward on MI355X.
// memset counts -> hist(dst) -> 3-phase scan -> fill_csr -> convw (W->bf16^T)
//   -> mfma_gemm1 (x fp32->bf16 frags @ W1t, *dinv, out bf16 h1)
//   -> agg1  (bf16 gather, fp32 acc, +b1, relu, out bf16 h1a)
//   -> mfma_gemm2 (h1a bf16 @ W2t, *dinv, out bf16 h2)
//   -> agg2  (bf16 gather 32 lanes/node, +b2, log_softmax, fp32 out)
// dinv folded into GEMM epilogue: hs[n] = (X@W)[n]*dinv[n];
//   out[n] = dn*(hs[n] + sum_nbr hs[s]) + b.
// Gather tables all bf16: L2-miss-path traffic is the bottleneck (R4: agg2
// FETCH 81MB @ 1.8TB/s on fp32 table; bf16 halves row bytes + table fits L2s).
// ---------------------------------------------------------------------------

typedef unsigned int uint32;
typedef __attribute__((ext_vector_type(8))) short bf16x8;
typedef __attribute__((ext_vector_type(4))) float f32x4;

__device__ inline unsigned short f2bf_rne(float f) {
    uint32 x = __float_as_uint(f);
    uint32 r = (x + 0x7fffu + ((x >> 16) & 1u)) >> 16;
    return (unsigned short)r;
}
__device__ inline uint32 pack_bf16x2(float a, float b) {
    return (uint32)f2bf_rne(a) | ((uint32)f2bf_rne(b) << 16);
}
__device__ inline float2 unpack_bf16x2(uint32 u) {
    float2 r;
    r.x = __uint_as_float(u << 16);
    r.y = __uint_as_float(u & 0xffff0000u);
    return r;
}

__global__ void hist_k(const int* __restrict__ dst, int E, int* __restrict__ counts) {
    int e = blockIdx.x * blockDim.x + threadIdx.x;
    if (e < E) atomicAdd(&counts[dst[e]], 1);
}

__global__ __launch_bounds__(256) void partial_scan_k(const int* __restrict__ counts, int N,
                                                      int* __restrict__ exscan,
                                                      int* __restrict__ blocksum,
                                                      float* __restrict__ dinv) {
    __shared__ int sd[256];
    const int tid = threadIdx.x;
    const int gid = blockIdx.x * 256 + tid;
    int v = (gid < N) ? counts[gid] : 0;
    sd[tid] = v;
    __syncthreads();
    for (int off = 1; off < 256; off <<= 1) {
        int t = (tid >= off) ? sd[tid - off] : 0;
        __syncthreads();
        sd[tid] += t;
        __syncthreads();
    }
    if (gid < N) {
        exscan[gid] = sd[tid] - v;
        dinv[gid]   = rsqrtf((float)(v + 1));
    }
    if (tid == 255) blocksum[blockIdx.x] = sd[255];
}

__global__ __launch_bounds__(256) void scan_blocksums_k(const int* __restrict__ blocksum, int NB,
                                                        int* __restrict__ blockoff,
                                                        int* __restrict__ offsets_last) {
    __shared__ int sd[256];
    const int tid = threadIdx.x;
    int v = (tid < NB) ? blocksum[tid] : 0;
    sd[tid] = v;
    __syncthreads();
    for (int off = 1; off < 256; off <<= 1) {
        int t = (tid >= off) ? sd[tid - off] : 0;
        __syncthreads();
        sd[tid] += t;
        __syncthreads();
    }
    if (tid < NB) blockoff[tid] = sd[tid] - v;
    if (tid == 255) *offsets_last = sd[255];
}

__global__ __launch_bounds__(256) void finalize_k(const int* __restrict__ exscan,
                                                  const int* __restrict__ blockoff, int N,
                                                  int* __restrict__ offsets,
                                                  int* __restrict__ cursor) {
    const int gid = blockIdx.x * 256 + threadIdx.x;
    if (gid < N) {
        int o = blockoff[blockIdx.x] + exscan[gid];
        offsets[gid] = o;
        cursor[gid]  = o;
    }
}

__global__ void fill_csr_k(const int* __restrict__ src, const int* __restrict__ dst, int E,
                           int* __restrict__ cursor, int* __restrict__ csr_src) {
    int e = blockIdx.x * blockDim.x + threadIdx.x;
    if (e < E) {
        int pos = atomicAdd(&cursor[dst[e]], 1);
        csr_src[pos] = src[e];
    }
}

// W1 [128][128] and W2 [128][64] fp32 row-major -> bf16 transposed [n][k].
__global__ __launch_bounds__(256) void convw_k(const float* __restrict__ W1,
                                               const float* __restrict__ W2,
                                               unsigned short* __restrict__ W1t,
                                               unsigned short* __restrict__ W2t) {
    int idx = blockIdx.x * 256 + threadIdx.x;
    if (idx < 128 * 128) {
        int n = idx >> 7, k = idx & 127;
        W1t[idx] = f2bf_rne(W1[k * 128 + n]);
    } else {
        int i2 = idx - 128 * 128;
        if (i2 < 64 * 128) {
            int n = i2 >> 7, k = i2 & 127;
            W2t[i2] = f2bf_rne(W2[k * 64 + n]);
        }
    }
}

// MFMA GEMM: Y[r,:] = (X[r,:128] @ W) * dinv[r].
// Wt: [NCOL][128] bf16 transposed. Block = 4 waves, wave = 16 rows x NCOL.
// ABF: X is bf16 (else fp32, converted in-register). YBF: Y stored bf16.
template <int NCOL, bool ABF, bool YBF>
__global__ __launch_bounds__(256) void mfma_gemm_k(const void* __restrict__ Xv,
                                                   const unsigned short* __restrict__ Wt,
                                                   const float* __restrict__ dinv,
                                                   void* __restrict__ Yv, int Nrows) {
    constexpr int NT = NCOL / 16;  // n-tiles per wave
    const int tid  = threadIdx.x;
    const int wave = tid >> 6;
    const int lane = tid & 63;
    const int m16  = lane & 15;
    const int q    = lane >> 4;
    const int r0   = blockIdx.x * 64 + wave * 16;

    int arow = r0 + m16;
    if (arow >= Nrows) arow = Nrows - 1;

    bf16x8 afrag[4];
    if (ABF) {
        const unsigned short* X = (const unsigned short*)Xv;
#pragma unroll
        for (int kb = 0; kb < 4; ++kb)
            afrag[kb] = *(const bf16x8*)&X[(size_t)arow * 128 + kb * 32 + q * 8];
    } else {
        const float* X = (const float*)Xv;
#pragma unroll
        for (int kb = 0; kb < 4; ++kb) {
            const float* p = &X[(size_t)arow * 128 + kb * 32 + q * 8];
            float4 u0 = *(const float4*)p;
            float4 u1 = *(const float4*)(p + 4);
            bf16x8 a;
            a[0] = (short)f2bf_rne(u0.x); a[1] = (short)f2bf_rne(u0.y);
            a[2] = (short)f2bf_rne(u0.z); a[3] = (short)f2bf_rne(u0.w);
            a[4] = (short)f2bf_rne(u1.x); a[5] = (short)f2bf_rne(u1.y);
            a[6] = (short)f2bf_rne(u1.z); a[7] = (short)f2bf_rne(u1.w);
            afrag[kb] = a;
        }
    }

    f32x4 acc[NT];
#pragma unroll
    for (int t = 0; t < NT; ++t) acc[t] = (f32x4){0.f, 0.f, 0.f, 0.f};

#pragma unroll
    for (int t = 0; t < NT; ++t) {
        const unsigned short* Bp = &Wt[(size_t)(t * 16 + m16) * 128 + q * 8];
#pragma unroll
        for (int kb = 0; kb < 4; ++kb) {
            bf16x8 bfrag = *(const bf16x8*)&Bp[kb * 32];
            acc[t] = __builtin_amdgcn_mfma_f32_16x16x32_bf16(afrag[kb], bfrag, acc[t], 0, 0, 0);
        }
    }

#pragma unroll
    for (int i = 0; i < 4; ++i) {
        int row = r0 + q * 4 + i;
        if (row < Nrows) {
            float dn = dinv[row];
#pragma unroll
            for (int t = 0; t < NT; ++t) {
                float v = acc[t][i] * dn;
                int col = t * 16 + m16;
                if (YBF)
                    ((unsigned short*)Yv)[(size_t)row * NCOL + col] = f2bf_rne(v);
                else
                    ((float*)Yv)[(size_t)row * NCOL + col] = v;
            }
        }
    }
}

// Layer-1 aggregation on bf16 table: 64 lanes/node, 2 ch/lane (packed uint),
// 4 nodes per 256-thread block, edge loop unrolled x4 (4 outstanding gathers).
// out = relu(dn*(self + sum nbr) + b1), bf16 out.
__global__ __launch_bounds__(256) void agg1_k(const unsigned short* __restrict__ hs,
                                              const int* __restrict__ offsets,
                                              const int* __restrict__ csr_src,
                                              const float* __restrict__ dinv,
                                              const float* __restrict__ b1,
                                              unsigned short* __restrict__ out, int N) {
    const int tid  = threadIdx.x;
    const int node = blockIdx.x * 4 + (tid >> 6);
    const int lane = tid & 63;
    if (node >= N) return;
    const uint32* T = (const uint32*)hs;
    const int start = offsets[node];
    const int end   = offsets[node + 1];
    const float dn  = dinv[node];
    float2 self = unpack_bf16x2(T[(size_t)node * 64 + lane]);
    float ax0 = self.x, ay0 = self.y;
    float ax1 = 0.f, ay1 = 0.f, ax2 = 0.f, ay2 = 0.f, ax3 = 0.f, ay3 = 0.f;
    int p = start;
    for (; p + 3 < end; p += 4) {
        int s0 = csr_src[p];
        int s1 = csr_src[p + 1];
        int s2 = csr_src[p + 2];
        int s3 = csr_src[p + 3];
        float2 f0 = unpack_bf16x2(T[(size_t)s0 * 64 + lane]);
        float2 f1 = unpack_bf16x2(T[(size_t)s1 * 64 + lane]);
        float2 f2 = unpack_bf16x2(T[(size_t)s2 * 64 + lane]);
        float2 f3 = unpack_bf16x2(T[(size_t)s3 * 64 + lane]);
        ax0 += f0.x; ay0 += f0.y;
        ax1 += f1.x; ay1 += f1.y;
        ax2 += f2.x; ay2 += f2.y;
        ax3 += f3.x; ay3 += f3.y;
    }
    for (; p < end; ++p) {
        float2 f = unpack_bf16x2(T[(size_t)csr_src[p] * 64 + lane]);
        ax1 += f.x; ay1 += f.y;
    }
    float2 bb = ((const float2*)b1)[lane];
    float vx = ((ax0 + ax1) + (ax2 + ax3)) * dn + bb.x;
    float vy = ((ay0 + ay1) + (ay2 + ay3)) * dn + bb.y;
    vx = vx > 0.f ? vx : 0.f;
    vy = vy > 0.f ? vy : 0.f;
    ((uint32*)out)[(size_t)node * 64 + lane] = pack_bf16x2(vx, vy);
}

// Layer-2 aggregation + bias + log_softmax on bf16 table.
// 32 lanes/node, 2 ch/lane; 8 nodes per 256-thread block; unrolled x4.
// Softmax reduction over the 32-lane half-wave (xor offs <=16) + channel pair.
__global__ __launch_bounds__(256) void agg2_k(const unsigned short* __restrict__ hs,
                                              const int* __restrict__ offsets,
                                              const int* __restrict__ csr_src,
                                              const float* __restrict__ dinv,
                                              const float* __restrict__ b2,
                                              float* __restrict__ out, int N) {
    const int tid  = threadIdx.x;
    const int node = blockIdx.x * 8 + (tid >> 5);
    const int l    = tid & 31;  // channels 2l, 2l+1
    if (node >= N) return;
    const uint32* T = (const uint32*)hs;  // row stride 32 uints
    const int start = offsets[node];
    const int end   = offsets[node + 1];
    const float dn  = dinv[node];
    float2 self = unpack_bf16x2(T[(size_t)node * 32 + l]);
    float ax0 = self.x, ay0 = self.y;
    float ax1 = 0.f, ay1 = 0.f, ax2 = 0.f, ay2 = 0.f, ax3 = 0.f, ay3 = 0.f;
    int p = start;
    for (; p + 3 < end; p += 4) {
        int s0 = csr_src[p];
        int s1 = csr_src[p + 1];
        int s2 = csr_src[p + 2];
        int s3 = csr_src[p + 3];
        float2 f0 = unpack_bf16x2(T[(size_t)s0 * 32 + l]);
        float2 f1 = unpack_bf16x2(T[(size_t)s1 * 32 + l]);
        float2 f2 = unpack_bf16x2(T[(size_t)s2 * 32 + l]);
        float2 f3 = unpack_bf16x2(T[(size_t)s3 * 32 + l]);
        ax0 += f0.x; ay0 += f0.y;
        ax1 += f1.x; ay1 += f1.y;
        ax2 += f2.x; ay2 += f2.y;
        ax3 += f3.x; ay3 += f3.y;
    }
    for (; p < end; ++p) {
        float2 f = unpack_bf16x2(T[(size_t)csr_src[p] * 32 + l]);
        ax1 += f.x; ay1 += f.y;
    }
    float2 bb = ((const float2*)b2)[l];
    float vx = ((ax0 + ax1) + (ax2 + ax3)) * dn + bb.x;
    float vy = ((ay0 + ay1) + (ay2 + ay3)) * dn + bb.y;
    float m = fmaxf(vx, vy);
#pragma unroll
    for (int off = 16; off > 0; off >>= 1) m = fmaxf(m, __shfl_xor(m, off, 64));
    float ex = __expf(vx - m) + __expf(vy - m);
    float ssum = ex;
#pragma unroll
    for (int off = 16; off > 0; off >>= 1) ssum += __shfl_xor(ssum, off, 64);
    float lse = m + __logf(ssum);
    float2 o = {vx - lse, vy - lse};
    ((float2*)out)[(size_t)node * 32 + l] = o;
}

extern "C" void kernel_launch(void* const* d_in, const int* in_sizes, int n_in,
                              void* d_out, int out_size, void* d_ws, size_t ws_size,
                              hipStream_t stream) {
    const float* x  = (const float*)d_in[0];
    const int*   ei = (const int*)d_in[1];
    const float* W1 = (const float*)d_in[2];
    const float* b1 = (const float*)d_in[3];
    const float* W2 = (const float*)d_in[4];
    const float* b2 = (const float*)d_in[5];
    float* out = (float*)d_out;

    const int N = in_sizes[0] / 128;  // 50000
    const int E = in_sizes[1] / 2;    // 800000
    const int* src = ei;
    const int* dst = ei + E;
    const int NB = (N + 255) / 256;

    char* ws = (char*)d_ws;
    auto alloc = [&](size_t bytes) -> char* {
        char* p = ws;
        ws += (bytes + 255) & ~(size_t)255;
        return p;
    };
    unsigned short* h1  = (unsigned short*)alloc((size_t)N * 128 * 2);  // bf16
    unsigned short* h1a = (unsigned short*)alloc((size_t)N * 128 * 2);  // bf16
    unsigned short* h2  = (unsigned short*)alloc((size_t)N * 64 * 2);   // bf16
    float* dinv     = (float*)alloc((size_t)N * 4);
    int*   counts   = (int*)alloc((size_t)N * 4);
    int*   exscan   = (int*)alloc((size_t)N * 4);
    int*   blocksum = (int*)alloc((size_t)NB * 4);
    int*   blockoff = (int*)alloc((size_t)NB * 4);
    int*   offsets  = (int*)alloc((size_t)(N + 1) * 4);
    int*   cursor   = (int*)alloc((size_t)N * 4);
    int*   csr_src  = (int*)alloc((size_t)E * 4);
    unsigned short* W1t = (unsigned short*)alloc(128 * 128 * 2);
    unsigned short* W2t = (unsigned short*)alloc(64 * 128 * 2);

    hipMemsetAsync(counts, 0, (size_t)N * 4, stream);
    hist_k<<<(E + 255) / 256, 256, 0, stream>>>(dst, E, counts);
    partial_scan_k<<<NB, 256, 0, stream>>>(counts, N, exscan, blocksum, dinv);
    scan_blocksums_k<<<1, 256, 0, stream>>>(blocksum, NB, blockoff, offsets + N);
    finalize_k<<<NB, 256, 0, stream>>>(exscan, blockoff, N, offsets, cursor);
    fill_csr_k<<<(E + 255) / 256, 256, 0, stream>>>(src, dst, E, cursor, csr_src);
    convw_k<<<(128 * 128 + 64 * 128 + 255) / 256, 256, 0, stream>>>(W1, W2, W1t, W2t);

    const int GB = (N + 63) / 64;
    mfma_gemm_k<128, false, true><<<GB, 256, 0, stream>>>(x, W1t, dinv, h1, N);
    agg1_k<<<(N + 3) / 4, 256, 0, stream>>>(h1, offsets, csr_src, dinv, b1, h1a, N);
    mfma_gemm_k<64, true, true><<<GB, 256, 0, stream>>>(h1a, W2t, dinv, h2, N);
    agg2_k<<<(N + 7) / 8, 256, 0, stream>>>(h2, offsets, csr_src, dinv, b2, out, N);
}

// Round 6
// 263.975 us; speedup vs baseline: 1.5363x; 1.0419x over previous
//
#include <hip/hip_runtime.h>
#include <hip/hip_bf16.h>
#include <math.h>

// ---------------------------------------------------------------------------
// GCN 2-layer forward on MI355X.
//  memset(counts) -> convw(W->bf16^T)
//  -> FUSED [hist(dst) || mfma_gemm1 (x @ W1t, UNscaled, out bf16 h1)]
//  -> 3-phase scan (offsets, cursor, dinv)
//  -> FUSED [fill_csr (x4-ILP atomics) || scale h1 *= dinv[row]]
//  -> agg1 (bf16 gather, +b1, relu, bf16 h1a)
//  -> mfma_gemm2 (h1a @ W2t, *dinv, bf16 h2)
//  -> agg2 (bf16 gather 32 lanes/node, +b2, log_softmax)
// R5 analysis: fill_csr was atomic-latency x MLP bound (1 outstanding
// atomic/wave). x4 ILP quadruples outstanding atomics; graph-build kernels
// leave VALU/MFMA idle so gemm1/scale ride along free (block-range fusion).
// ---------------------------------------------------------------------------

typedef unsigned int uint32;
typedef __attribute__((ext_vector_type(8))) short bf16x8;
typedef __attribute__((ext_vector_type(4))) float f32x4;

__device__ inline unsigned short f2bf_rne(float f) {
    uint32 x = __float_as_uint(f);
    uint32 r = (x + 0x7fffu + ((x >> 16) & 1u)) >> 16;
    return (unsigned short)r;
}
__device__ inline uint32 pack_bf16x2(float a, float b) {
    return (uint32)f2bf_rne(a) | ((uint32)f2bf_rne(b) << 16);
}
__device__ inline float2 unpack_bf16x2(uint32 u) {
    float2 r;
    r.x = __uint_as_float(u << 16);
    r.y = __uint_as_float(u & 0xffff0000u);
    return r;
}

// W1 [128][128] and W2 [128][64] fp32 row-major -> bf16 transposed [n][k].
__global__ __launch_bounds__(256) void convw_k(const float* __restrict__ W1,
                                               const float* __restrict__ W2,
                                               unsigned short* __restrict__ W1t,
                                               unsigned short* __restrict__ W2t) {
    int idx = blockIdx.x * 256 + threadIdx.x;
    if (idx < 128 * 128) {
        int n = idx >> 7, k = idx & 127;
        W1t[idx] = f2bf_rne(W1[k * 128 + n]);
    } else {
        int i2 = idx - 128 * 128;
        if (i2 < 64 * 128) {
            int n = i2 >> 7, k = i2 & 127;
            W2t[i2] = f2bf_rne(W2[k * 64 + n]);
        }
    }
}

// FUSED: blocks [0,HB) histogram dst with x4 ILP; blocks [HB,HB+GB) do
// mfma gemm1: h1[r,:] = bf16( x[r,:] @ W1t )   (unscaled; dinv not ready yet)
__global__ __launch_bounds__(256) void hist_gemm1_k(const int* __restrict__ dst, int E,
                                                    int* __restrict__ counts,
                                                    const float* __restrict__ X,
                                                    const unsigned short* __restrict__ Wt,
                                                    unsigned short* __restrict__ Y,
                                                    int Nrows, int HB) {
    if ((int)blockIdx.x < HB) {
        const int T = HB * 256;
        const int i = blockIdx.x * 256 + threadIdx.x;
#pragma unroll
        for (int j = 0; j < 4; ++j) {
            int e = i + j * T;
            if (e < E) atomicAdd(&counts[dst[e]], 1);
        }
        return;
    }
    // ---- gemm1 part (NCOL=128, fp32 A converted in-register) ----
    constexpr int NCOL = 128;
    constexpr int NT = NCOL / 16;
    const int tid  = threadIdx.x;
    const int wave = tid >> 6;
    const int lane = tid & 63;
    const int m16  = lane & 15;
    const int q    = lane >> 4;
    const int r0   = ((int)blockIdx.x - HB) * 64 + wave * 16;

    int arow = r0 + m16;
    if (arow >= Nrows) arow = Nrows - 1;

    bf16x8 afrag[4];
#pragma unroll
    for (int kb = 0; kb < 4; ++kb) {
        const float* p = &X[(size_t)arow * 128 + kb * 32 + q * 8];
        float4 u0 = *(const float4*)p;
        float4 u1 = *(const float4*)(p + 4);
        bf16x8 a;
        a[0] = (short)f2bf_rne(u0.x); a[1] = (short)f2bf_rne(u0.y);
        a[2] = (short)f2bf_rne(u0.z); a[3] = (short)f2bf_rne(u0.w);
        a[4] = (short)f2bf_rne(u1.x); a[5] = (short)f2bf_rne(u1.y);
        a[6] = (short)f2bf_rne(u1.z); a[7] = (short)f2bf_rne(u1.w);
        afrag[kb] = a;
    }

    f32x4 acc[NT];
#pragma unroll
    for (int t = 0; t < NT; ++t) acc[t] = (f32x4){0.f, 0.f, 0.f, 0.f};
#pragma unroll
    for (int t = 0; t < NT; ++t) {
        const unsigned short* Bp = &Wt[(size_t)(t * 16 + m16) * 128 + q * 8];
#pragma unroll
        for (int kb = 0; kb < 4; ++kb) {
            bf16x8 bfrag = *(const bf16x8*)&Bp[kb * 32];
            acc[t] = __builtin_amdgcn_mfma_f32_16x16x32_bf16(afrag[kb], bfrag, acc[t], 0, 0, 0);
        }
    }
#pragma unroll
    for (int i = 0; i < 4; ++i) {
        int row = r0 + q * 4 + i;
        if (row < Nrows) {
#pragma unroll
            for (int t = 0; t < NT; ++t)
                Y[(size_t)row * NCOL + t * 16 + m16] = f2bf_rne(acc[t][i]);
        }
    }
}

__global__ __launch_bounds__(256) void partial_scan_k(const int* __restrict__ counts, int N,
                                                      int* __restrict__ exscan,
                                                      int* __restrict__ blocksum,
                                                      float* __restrict__ dinv) {
    __shared__ int sd[256];
    const int tid = threadIdx.x;
    const int gid = blockIdx.x * 256 + tid;
    int v = (gid < N) ? counts[gid] : 0;
    sd[tid] = v;
    __syncthreads();
    for (int off = 1; off < 256; off <<= 1) {
        int t = (tid >= off) ? sd[tid - off] : 0;
        __syncthreads();
        sd[tid] += t;
        __syncthreads();
    }
    if (gid < N) {
        exscan[gid] = sd[tid] - v;
        dinv[gid]   = rsqrtf((float)(v + 1));
    }
    if (tid == 255) blocksum[blockIdx.x] = sd[255];
}

__global__ __launch_bounds__(256) void scan_blocksums_k(const int* __restrict__ blocksum, int NB,
                                                        int* __restrict__ blockoff,
                                                        int* __restrict__ offsets_last) {
    __shared__ int sd[256];
    const int tid = threadIdx.x;
    int v = (tid < NB) ? blocksum[tid] : 0;
    sd[tid] = v;
    __syncthreads();
    for (int off = 1; off < 256; off <<= 1) {
        int t = (tid >= off) ? sd[tid - off] : 0;
        __syncthreads();
        sd[tid] += t;
        __syncthreads();
    }
    if (tid < NB) blockoff[tid] = sd[tid] - v;
    if (tid == 255) *offsets_last = sd[255];
}

__global__ __launch_bounds__(256) void finalize_k(const int* __restrict__ exscan,
                                                  const int* __restrict__ blockoff, int N,
                                                  int* __restrict__ offsets,
                                                  int* __restrict__ cursor) {
    const int gid = blockIdx.x * 256 + threadIdx.x;
    if (gid < N) {
        int o = blockoff[blockIdx.x] + exscan[gid];
        offsets[gid] = o;
        cursor[gid]  = o;
    }
}

// FUSED: blocks [0,FB) fill CSR with x4-ILP atomic-with-return;
// blocks [FB,FB+SB) scale h1 rows by dinv (in-place, packed bf16x2).
__global__ __launch_bounds__(256) void fill_scale_k(const int* __restrict__ src,
                                                    const int* __restrict__ dst, int E,
                                                    int* __restrict__ cursor,
                                                    int* __restrict__ csr_src,
                                                    uint32* __restrict__ H, int U,
                                                    const float* __restrict__ dinv,
                                                    int FB, int SB) {
    if ((int)blockIdx.x < FB) {
        const int T = FB * 256;
        const int i = blockIdx.x * 256 + threadIdx.x;
        int d[4], s[4];
        bool v[4];
#pragma unroll
        for (int j = 0; j < 4; ++j) {
            int e = i + j * T;
            v[j] = e < E;
            if (v[j]) { d[j] = dst[e]; s[j] = src[e]; }
        }
        int pos[4];
#pragma unroll
        for (int j = 0; j < 4; ++j)
            if (v[j]) pos[j] = atomicAdd(&cursor[d[j]], 1);
#pragma unroll
        for (int j = 0; j < 4; ++j)
            if (v[j]) csr_src[pos[j]] = s[j];
        return;
    }
    // ---- scale part: H[idx] (2 channels) *= dinv[idx>>6] ----
    const int T2 = SB * 256;
    const int i = ((int)blockIdx.x - FB) * 256 + threadIdx.x;
#pragma unroll
    for (int j = 0; j < 4; ++j) {
        int idx = i + j * T2;
        if (idx < U) {
            float dn = dinv[idx >> 6];
            float2 f = unpack_bf16x2(H[idx]);
            H[idx] = pack_bf16x2(f.x * dn, f.y * dn);
        }
    }
}

// MFMA GEMM2: Y[r,:] = bf16( (X[r,:128] @ W) * dinv[r] ).  X bf16.
__global__ __launch_bounds__(256) void mfma_gemm2_k(const unsigned short* __restrict__ X,
                                                    const unsigned short* __restrict__ Wt,
                                                    const float* __restrict__ dinv,
                                                    unsigned short* __restrict__ Y, int Nrows) {
    constexpr int NCOL = 64;
    constexpr int NT = NCOL / 16;
    const int tid  = threadIdx.x;
    const int wave = tid >> 6;
    const int lane = tid & 63;
    const int m16  = lane & 15;
    const int q    = lane >> 4;
    const int r0   = blockIdx.x * 64 + wave * 16;

    int arow = r0 + m16;
    if (arow >= Nrows) arow = Nrows - 1;

    bf16x8 afrag[4];
#pragma unroll
    for (int kb = 0; kb < 4; ++kb)
        afrag[kb] = *(const bf16x8*)&X[(size_t)arow * 128 + kb * 32 + q * 8];

    f32x4 acc[NT];
#pragma unroll
    for (int t = 0; t < NT; ++t) acc[t] = (f32x4){0.f, 0.f, 0.f, 0.f};
#pragma unroll
    for (int t = 0; t < NT; ++t) {
        const unsigned short* Bp = &Wt[(size_t)(t * 16 + m16) * 128 + q * 8];
#pragma unroll
        for (int kb = 0; kb < 4; ++kb) {
            bf16x8 bfrag = *(const bf16x8*)&Bp[kb * 32];
            acc[t] = __builtin_amdgcn_mfma_f32_16x16x32_bf16(afrag[kb], bfrag, acc[t], 0, 0, 0);
        }
    }
#pragma unroll
    for (int i = 0; i < 4; ++i) {
        int row = r0 + q * 4 + i;
        if (row < Nrows) {
            float dn = dinv[row];
#pragma unroll
            for (int t = 0; t < NT; ++t)
                Y[(size_t)row * NCOL + t * 16 + m16] = f2bf_rne(acc[t][i] * dn);
        }
    }
}

// Layer-1 aggregation on bf16 table: 64 lanes/node, 2 ch/lane (packed uint),
// 4 nodes per 256-thread block, edge loop unrolled x4.
// out = relu(dn*(self + sum nbr) + b1), bf16 out.
__global__ __launch_bounds__(256) void agg1_k(const unsigned short* __restrict__ hs,
                                              const int* __restrict__ offsets,
                                              const int* __restrict__ csr_src,
                                              const float* __restrict__ dinv,
                                              const float* __restrict__ b1,
                                              unsigned short* __restrict__ out, int N) {
    const int tid  = threadIdx.x;
    const int node = blockIdx.x * 4 + (tid >> 6);
    const int lane = tid & 63;
    if (node >= N) return;
    const uint32* T = (const uint32*)hs;
    const int start = offsets[node];
    const int end   = offsets[node + 1];
    const float dn  = dinv[node];
    float2 self = unpack_bf16x2(T[(size_t)node * 64 + lane]);
    float ax0 = self.x, ay0 = self.y;
    float ax1 = 0.f, ay1 = 0.f, ax2 = 0.f, ay2 = 0.f, ax3 = 0.f, ay3 = 0.f;
    int p = start;
    for (; p + 3 < end; p += 4) {
        int s0 = csr_src[p];
        int s1 = csr_src[p + 1];
        int s2 = csr_src[p + 2];
        int s3 = csr_src[p + 3];
        float2 f0 = unpack_bf16x2(T[(size_t)s0 * 64 + lane]);
        float2 f1 = unpack_bf16x2(T[(size_t)s1 * 64 + lane]);
        float2 f2 = unpack_bf16x2(T[(size_t)s2 * 64 + lane]);
        float2 f3 = unpack_bf16x2(T[(size_t)s3 * 64 + lane]);
        ax0 += f0.x; ay0 += f0.y;
        ax1 += f1.x; ay1 += f1.y;
        ax2 += f2.x; ay2 += f2.y;
        ax3 += f3.x; ay3 += f3.y;
    }
    for (; p < end; ++p) {
        float2 f = unpack_bf16x2(T[(size_t)csr_src[p] * 64 + lane]);
        ax1 += f.x; ay1 += f.y;
    }
    float2 bb = ((const float2*)b1)[lane];
    float vx = ((ax0 + ax1) + (ax2 + ax3)) * dn + bb.x;
    float vy = ((ay0 + ay1) + (ay2 + ay3)) * dn + bb.y;
    vx = vx > 0.f ? vx : 0.f;
    vy = vy > 0.f ? vy : 0.f;
    ((uint32*)out)[(size_t)node * 64 + lane] = pack_bf16x2(vx, vy);
}

// Layer-2 aggregation + bias + log_softmax on bf16 table.
// 32 lanes/node, 2 ch/lane; 8 nodes per 256-thread block; unrolled x4.
__global__ __launch_bounds__(256) void agg2_k(const unsigned short* __restrict__ hs,
                                              const int* __restrict__ offsets,
                                              const int* __restrict__ csr_src,
                                              const float* __restrict__ dinv,
                                              const float* __restrict__ b2,
                                              float* __restrict__ out, int N) {
    const int tid  = threadIdx.x;
    const int node = blockIdx.x * 8 + (tid >> 5);
    const int l    = tid & 31;
    if (node >= N) return;
    const uint32* T = (const uint32*)hs;
    const int start = offsets[node];
    const int end   = offsets[node + 1];
    const float dn  = dinv[node];
    float2 self = unpack_bf16x2(T[(size_t)node * 32 + l]);
    float ax0 = self.x, ay0 = self.y;
    float ax1 = 0.f, ay1 = 0.f, ax2 = 0.f, ay2 = 0.f, ax3 = 0.f, ay3 = 0.f;
    int p = start;
    for (; p + 3 < end; p += 4) {
        int s0 = csr_src[p];
        int s1 = csr_src[p + 1];
        int s2 = csr_src[p + 2];
        int s3 = csr_src[p + 3];
        float2 f0 = unpack_bf16x2(T[(size_t)s0 * 32 + l]);
        float2 f1 = unpack_bf16x2(T[(size_t)s1 * 32 + l]);
        float2 f2 = unpack_bf16x2(T[(size_t)s2 * 32 + l]);
        float2 f3 = unpack_bf16x2(T[(size_t)s3 * 32 + l]);
        ax0 += f0.x; ay0 += f0.y;
        ax1 += f1.x; ay1 += f1.y;
        ax2 += f2.x; ay2 += f2.y;
        ax3 += f3.x; ay3 += f3.y;
    }
    for (; p < end; ++p) {
        float2 f = unpack_bf16x2(T[(size_t)csr_src[p] * 32 + l]);
        ax1 += f.x; ay1 += f.y;
    }
    float2 bb = ((const float2*)b2)[l];
    float vx = ((ax0 + ax1) + (ax2 + ax3)) * dn + bb.x;
    float vy = ((ay0 + ay1) + (ay2 + ay3)) * dn + bb.y;
    float m = fmaxf(vx, vy);
#pragma unroll
    for (int off = 16; off > 0; off >>= 1) m = fmaxf(m, __shfl_xor(m, off, 64));
    float ex = __expf(vx - m) + __expf(vy - m);
    float ssum = ex;
#pragma unroll
    for (int off = 16; off > 0; off >>= 1) ssum += __shfl_xor(ssum, off, 64);
    float lse = m + __logf(ssum);
    float2 o = {vx - lse, vy - lse};
    ((float2*)out)[(size_t)node * 32 + l] = o;
}

extern "C" void kernel_launch(void* const* d_in, const int* in_sizes, int n_in,
                              void* d_out, int out_size, void* d_ws, size_t ws_size,
                              hipStream_t stream) {
    const float* x  = (const float*)d_in[0];
    const int*   ei = (const int*)d_in[1];
    const float* W1 = (const float*)d_in[2];
    const float* b1 = (const float*)d_in[3];
    const float* W2 = (const float*)d_in[4];
    const float* b2 = (const float*)d_in[5];
    float* out = (float*)d_out;

    const int N = in_sizes[0] / 128;  // 50000
    const int E = in_sizes[1] / 2;    // 800000
    const int* src = ei;
    const int* dst = ei + E;
    const int NB = (N + 255) / 256;

    char* ws = (char*)d_ws;
    auto alloc = [&](size_t bytes) -> char* {
        char* p = ws;
        ws += (bytes + 255) & ~(size_t)255;
        return p;
    };
    unsigned short* h1  = (unsigned short*)alloc((size_t)N * 128 * 2);  // bf16
    unsigned short* h1a = (unsigned short*)alloc((size_t)N * 128 * 2);  // bf16
    unsigned short* h2  = (unsigned short*)alloc((size_t)N * 64 * 2);   // bf16
    float* dinv     = (float*)alloc((size_t)N * 4);
    int*   counts   = (int*)alloc((size_t)N * 4);
    int*   exscan   = (int*)alloc((size_t)N * 4);
    int*   blocksum = (int*)alloc((size_t)NB * 4);
    int*   blockoff = (int*)alloc((size_t)NB * 4);
    int*   offsets  = (int*)alloc((size_t)(N + 1) * 4);
    int*   cursor   = (int*)alloc((size_t)N * 4);
    int*   csr_src  = (int*)alloc((size_t)E * 4);
    unsigned short* W1t = (unsigned short*)alloc(128 * 128 * 2);
    unsigned short* W2t = (unsigned short*)alloc(64 * 128 * 2);

    const int HB = (E + 1023) / 1024;      // 782 hist blocks (x4 ILP)
    const int GB = (N + 63) / 64;          // 782 gemm blocks
    const int FB = (E + 1023) / 1024;      // 782 fill blocks (x4 ILP)
    const int U  = N * 64;                 // h1 packed-uint count
    const int SB = (U + 1023) / 1024;      // 3125 scale blocks (x4 ILP)

    hipMemsetAsync(counts, 0, (size_t)N * 4, stream);
    convw_k<<<(128 * 128 + 64 * 128 + 255) / 256, 256, 0, stream>>>(W1, W2, W1t, W2t);
    hist_gemm1_k<<<HB + GB, 256, 0, stream>>>(dst, E, counts, x, W1t, h1, N, HB);
    partial_scan_k<<<NB, 256, 0, stream>>>(counts, N, exscan, blocksum, dinv);
    scan_blocksums_k<<<1, 256, 0, stream>>>(blocksum, NB, blockoff, offsets + N);
    finalize_k<<<NB, 256, 0, stream>>>(exscan, blockoff, N, offsets, cursor);
    fill_scale_k<<<FB + SB, 256, 0, stream>>>(src, dst, E, cursor, csr_src,
                                              (uint32*)h1, U, dinv, FB, SB);
    agg1_k<<<(N + 3) / 4, 256, 0, stream>>>(h1, offsets, csr_src, dinv, b1, h1a, N);
    mfma_gemm2_k<<<GB, 256, 0, stream>>>(h1a, W2t, dinv, h2, N);
    agg2_k<<<(N + 7) / 8, 256, 0, stream>>>(h2, offsets, csr_src, dinv, b2, out, N);
}

// Round 7
// 250.198 us; speedup vs baseline: 1.6209x; 1.0551x over previous
//
#include <hip/hip_runtime.h>
#include <hip/hip_bf16.h>
#include <math.h>

// ---------------------------------------------------------------------------
// GCN 2-layer forward on MI355X.
//  memset(counts_p) -> convw(W->bf16^T, pair-permuted cols)
//  -> FUSED [hist(dst, x8 ILP, line-padded counters) || mfma_gemm1 (unscaled)]
//  -> 3-phase scan -> FUSED [fill_csr (x8 ILP, padded cursor) || h1 *= dinv]
//  -> agg1 (bf16 gather, +b1, relu) -> mfma_gemm2 (*dinv) -> agg2 (log_softmax)
// R6 analysis: hist atomics were line-serialization bound (800k atomics on
// 3125 cache lines; WRITE_SIZE showed ~32B/atomic memory-side RMW). Counters
// now padded to 1/128B line. GEMM C-stores pair-packed via W column permute.
// ---------------------------------------------------------------------------

typedef unsigned int uint32;
typedef __attribute__((ext_vector_type(8))) short bf16x8;
typedef __attribute__((ext_vector_type(4))) float f32x4;

#define PAD 5  // counter stride = 1<<PAD ints = 128 B

__device__ inline unsigned short f2bf_rne(float f) {
    uint32 x = __float_as_uint(f);
    uint32 r = (x + 0x7fffu + ((x >> 16) & 1u)) >> 16;
    return (unsigned short)r;
}
__device__ inline uint32 pack_bf16x2(float a, float b) {
    return (uint32)f2bf_rne(a) | ((uint32)f2bf_rne(b) << 16);
}
__device__ inline float2 unpack_bf16x2(uint32 u) {
    float2 r;
    r.x = __uint_as_float(u << 16);
    r.y = __uint_as_float(u & 0xffff0000u);
    return r;
}

// W -> bf16 transposed, pair-permuted: slot (t,m) holds logical column
// 32*(t>>1) + 2*m + (t&1), so acc pairs (t=2u,2u+1) pack to adjacent cols.
__global__ __launch_bounds__(256) void convw_k(const float* __restrict__ W1,
                                               const float* __restrict__ W2,
                                               unsigned short* __restrict__ W1t,
                                               unsigned short* __restrict__ W2t) {
    int idx = blockIdx.x * 256 + threadIdx.x;
    if (idx < 128 * 128) {
        int ns = idx >> 7, k = idx & 127;
        int t = ns >> 4, m = ns & 15;
        int col = 32 * (t >> 1) + 2 * m + (t & 1);
        W1t[idx] = f2bf_rne(W1[k * 128 + col]);
    } else {
        int i2 = idx - 128 * 128;
        if (i2 < 64 * 128) {
            int ns = i2 >> 7, k = i2 & 127;
            int t = ns >> 4, m = ns & 15;
            int col = 32 * (t >> 1) + 2 * m + (t & 1);
            W2t[i2] = f2bf_rne(W2[k * 64 + col]);
        }
    }
}

// FUSED: blocks [0,HB): histogram dst, x8 ILP, line-padded counters.
//        blocks [HB,HB+GB): mfma gemm1 h1 = bf16(x @ W1t) (unscaled).
__global__ __launch_bounds__(256) void hist_gemm1_k(const int* __restrict__ dst, int E,
                                                    int* __restrict__ counts_p,
                                                    const float* __restrict__ X,
                                                    const unsigned short* __restrict__ Wt,
                                                    uint32* __restrict__ Yu,
                                                    int Nrows, int HB) {
    if ((int)blockIdx.x < HB) {
        const int T = HB * 256;
        const int i = blockIdx.x * 256 + threadIdx.x;
#pragma unroll
        for (int j = 0; j < 8; ++j) {
            int e = i + j * T;
            if (e < E) atomicAdd(&counts_p[dst[e] << PAD], 1);
        }
        return;
    }
    constexpr int NCOL = 128;
    constexpr int NT = NCOL / 16;
    const int tid  = threadIdx.x;
    const int wave = tid >> 6;
    const int lane = tid & 63;
    const int m16  = lane & 15;
    const int q    = lane >> 4;
    const int r0   = ((int)blockIdx.x - HB) * 64 + wave * 16;

    int arow = r0 + m16;
    if (arow >= Nrows) arow = Nrows - 1;

    bf16x8 afrag[4];
#pragma unroll
    for (int kb = 0; kb < 4; ++kb) {
        const float* p = &X[(size_t)arow * 128 + kb * 32 + q * 8];
        float4 u0 = *(const float4*)p;
        float4 u1 = *(const float4*)(p + 4);
        bf16x8 a;
        a[0] = (short)f2bf_rne(u0.x); a[1] = (short)f2bf_rne(u0.y);
        a[2] = (short)f2bf_rne(u0.z); a[3] = (short)f2bf_rne(u0.w);
        a[4] = (short)f2bf_rne(u1.x); a[5] = (short)f2bf_rne(u1.y);
        a[6] = (short)f2bf_rne(u1.z); a[7] = (short)f2bf_rne(u1.w);
        afrag[kb] = a;
    }

    f32x4 acc[NT];
#pragma unroll
    for (int t = 0; t < NT; ++t) acc[t] = (f32x4){0.f, 0.f, 0.f, 0.f};
#pragma unroll
    for (int t = 0; t < NT; ++t) {
        const unsigned short* Bp = &Wt[(size_t)(t * 16 + m16) * 128 + q * 8];
#pragma unroll
        for (int kb = 0; kb < 4; ++kb) {
            bf16x8 bfrag = *(const bf16x8*)&Bp[kb * 32];
            acc[t] = __builtin_amdgcn_mfma_f32_16x16x32_bf16(afrag[kb], bfrag, acc[t], 0, 0, 0);
        }
    }
#pragma unroll
    for (int i = 0; i < 4; ++i) {
        int row = r0 + q * 4 + i;
        if (row < Nrows) {
#pragma unroll
            for (int u = 0; u < NT / 2; ++u)
                Yu[(size_t)row * (NCOL / 2) + u * 16 + m16] =
                    pack_bf16x2(acc[2 * u][i], acc[2 * u + 1][i]);
        }
    }
}

__global__ __launch_bounds__(256) void partial_scan_k(const int* __restrict__ counts_p, int N,
                                                      int* __restrict__ exscan,
                                                      int* __restrict__ blocksum,
                                                      float* __restrict__ dinv) {
    __shared__ int sd[256];
    const int tid = threadIdx.x;
    const int gid = blockIdx.x * 256 + tid;
    int v = (gid < N) ? counts_p[gid << PAD] : 0;
    sd[tid] = v;
    __syncthreads();
    for (int off = 1; off < 256; off <<= 1) {
        int t = (tid >= off) ? sd[tid - off] : 0;
        __syncthreads();
        sd[tid] += t;
        __syncthreads();
    }
    if (gid < N) {
        exscan[gid] = sd[tid] - v;
        dinv[gid]   = rsqrtf((float)(v + 1));
    }
    if (tid == 255) blocksum[blockIdx.x] = sd[255];
}

__global__ __launch_bounds__(256) void scan_blocksums_k(const int* __restrict__ blocksum, int NB,
                                                        int* __restrict__ blockoff,
                                                        int* __restrict__ offsets_last) {
    __shared__ int sd[256];
    const int tid = threadIdx.x;
    int v = (tid < NB) ? blocksum[tid] : 0;
    sd[tid] = v;
    __syncthreads();
    for (int off = 1; off < 256; off <<= 1) {
        int t = (tid >= off) ? sd[tid - off] : 0;
        __syncthreads();
        sd[tid] += t;
        __syncthreads();
    }
    if (tid < NB) blockoff[tid] = sd[tid] - v;
    if (tid == 255) *offsets_last = sd[255];
}

__global__ __launch_bounds__(256) void finalize_k(const int* __restrict__ exscan,
                                                  const int* __restrict__ blockoff, int N,
                                                  int* __restrict__ offsets,
                                                  int* __restrict__ cursor_p) {
    const int gid = blockIdx.x * 256 + threadIdx.x;
    if (gid < N) {
        int o = blockoff[blockIdx.x] + exscan[gid];
        offsets[gid] = o;
        cursor_p[gid << PAD] = o;
    }
}

// FUSED: blocks [0,FB): fill CSR, x8 ILP, padded cursor atomics.
//        blocks [FB,FB+SB): scale h1 (packed bf16x2) by dinv[row], x4 ILP.
__global__ __launch_bounds__(256) void fill_scale_k(const int* __restrict__ src,
                                                    const int* __restrict__ dst, int E,
                                                    int* __restrict__ cursor_p,
                                                    int* __restrict__ csr_src,
                                                    uint32* __restrict__ H, int U,
                                                    const float* __restrict__ dinv,
                                                    int FB, int SB) {
    if ((int)blockIdx.x < FB) {
        const int T = FB * 256;
        const int i = blockIdx.x * 256 + threadIdx.x;
        int d[8], s[8];
        bool v[8];
#pragma unroll
        for (int j = 0; j < 8; ++j) {
            int e = i + j * T;
            v[j] = e < E;
            if (v[j]) { d[j] = dst[e]; s[j] = src[e]; }
        }
        int pos[8];
#pragma unroll
        for (int j = 0; j < 8; ++j)
            if (v[j]) pos[j] = atomicAdd(&cursor_p[d[j] << PAD], 1);
#pragma unroll
        for (int j = 0; j < 8; ++j)
            if (v[j]) csr_src[pos[j]] = s[j];
        return;
    }
    const int T2 = SB * 256;
    const int i = ((int)blockIdx.x - FB) * 256 + threadIdx.x;
#pragma unroll
    for (int j = 0; j < 4; ++j) {
        int idx = i + j * T2;
        if (idx < U) {
            float dn = dinv[idx >> 6];
            float2 f = unpack_bf16x2(H[idx]);
            H[idx] = pack_bf16x2(f.x * dn, f.y * dn);
        }
    }
}

// MFMA GEMM2: h2[r,:] = bf16( (h1a[r,:128] @ W2t) * dinv[r] ), pair-packed stores.
__global__ __launch_bounds__(256) void mfma_gemm2_k(const unsigned short* __restrict__ X,
                                                    const unsigned short* __restrict__ Wt,
                                                    const float* __restrict__ dinv,
                                                    uint32* __restrict__ Yu, int Nrows) {
    constexpr int NCOL = 64;
    constexpr int NT = NCOL / 16;
    const int tid  = threadIdx.x;
    const int wave = tid >> 6;
    const int lane = tid & 63;
    const int m16  = lane & 15;
    const int q    = lane >> 4;
    const int r0   = blockIdx.x * 64 + wave * 16;

    int arow = r0 + m16;
    if (arow >= Nrows) arow = Nrows - 1;

    bf16x8 afrag[4];
#pragma unroll
    for (int kb = 0; kb < 4; ++kb)
        afrag[kb] = *(const bf16x8*)&X[(size_t)arow * 128 + kb * 32 + q * 8];

    f32x4 acc[NT];
#pragma unroll
    for (int t = 0; t < NT; ++t) acc[t] = (f32x4){0.f, 0.f, 0.f, 0.f};
#pragma unroll
    for (int t = 0; t < NT; ++t) {
        const unsigned short* Bp = &Wt[(size_t)(t * 16 + m16) * 128 + q * 8];
#pragma unroll
        for (int kb = 0; kb < 4; ++kb) {
            bf16x8 bfrag = *(const bf16x8*)&Bp[kb * 32];
            acc[t] = __builtin_amdgcn_mfma_f32_16x16x32_bf16(afrag[kb], bfrag, acc[t], 0, 0, 0);
        }
    }
#pragma unroll
    for (int i = 0; i < 4; ++i) {
        int row = r0 + q * 4 + i;
        if (row < Nrows) {
            float dn = dinv[row];
#pragma unroll
            for (int u = 0; u < NT / 2; ++u)
                Yu[(size_t)row * (NCOL / 2) + u * 16 + m16] =
                    pack_bf16x2(acc[2 * u][i] * dn, acc[2 * u + 1][i] * dn);
        }
    }
}

// Layer-1 aggregation: 64 lanes/node, 2 ch/lane, 4 nodes/block, x4 unroll.
__global__ __launch_bounds__(256) void agg1_k(const unsigned short* __restrict__ hs,
                                              const int* __restrict__ offsets,
                                              const int* __restrict__ csr_src,
                                              const float* __restrict__ dinv,
                                              const float* __restrict__ b1,
                                              unsigned short* __restrict__ out, int N) {
    const int tid  = threadIdx.x;
    const int node = blockIdx.x * 4 + (tid >> 6);
    const int lane = tid & 63;
    if (node >= N) return;
    const uint32* T = (const uint32*)hs;
    const int start = offsets[node];
    const int end   = offsets[node + 1];
    const float dn  = dinv[node];
    float2 self = unpack_bf16x2(T[(size_t)node * 64 + lane]);
    float ax0 = self.x, ay0 = self.y;
    float ax1 = 0.f, ay1 = 0.f, ax2 = 0.f, ay2 = 0.f, ax3 = 0.f, ay3 = 0.f;
    int p = start;
    for (; p + 3 < end; p += 4) {
        int s0 = csr_src[p];
        int s1 = csr_src[p + 1];
        int s2 = csr_src[p + 2];
        int s3 = csr_src[p + 3];
        float2 f0 = unpack_bf16x2(T[(size_t)s0 * 64 + lane]);
        float2 f1 = unpack_bf16x2(T[(size_t)s1 * 64 + lane]);
        float2 f2 = unpack_bf16x2(T[(size_t)s2 * 64 + lane]);
        float2 f3 = unpack_bf16x2(T[(size_t)s3 * 64 + lane]);
        ax0 += f0.x; ay0 += f0.y;
        ax1 += f1.x; ay1 += f1.y;
        ax2 += f2.x; ay2 += f2.y;
        ax3 += f3.x; ay3 += f3.y;
    }
    for (; p < end; ++p) {
        float2 f = unpack_bf16x2(T[(size_t)csr_src[p] * 64 + lane]);
        ax1 += f.x; ay1 += f.y;
    }
    float2 bb = ((const float2*)b1)[lane];
    float vx = ((ax0 + ax1) + (ax2 + ax3)) * dn + bb.x;
    float vy = ((ay0 + ay1) + (ay2 + ay3)) * dn + bb.y;
    vx = vx > 0.f ? vx : 0.f;
    vy = vy > 0.f ? vy : 0.f;
    ((uint32*)out)[(size_t)node * 64 + lane] = pack_bf16x2(vx, vy);
}

// Layer-2 aggregation + bias + log_softmax. 32 lanes/node, 8 nodes/block.
__global__ __launch_bounds__(256) void agg2_k(const unsigned short* __restrict__ hs,
                                              const int* __restrict__ offsets,
                                              const int* __restrict__ csr_src,
                                              const float* __restrict__ dinv,
                                              const float* __restrict__ b2,
                                              float* __restrict__ out, int N) {
    const int tid  = threadIdx.x;
    const int node = blockIdx.x * 8 + (tid >> 5);
    const int l    = tid & 31;
    if (node >= N) return;
    const uint32* T = (const uint32*)hs;
    const int start = offsets[node];
    const int end   = offsets[node + 1];
    const float dn  = dinv[node];
    float2 self = unpack_bf16x2(T[(size_t)node * 32 + l]);
    float ax0 = self.x, ay0 = self.y;
    float ax1 = 0.f, ay1 = 0.f, ax2 = 0.f, ay2 = 0.f, ax3 = 0.f, ay3 = 0.f;
    int p = start;
    for (; p + 3 < end; p += 4) {
        int s0 = csr_src[p];
        int s1 = csr_src[p + 1];
        int s2 = csr_src[p + 2];
        int s3 = csr_src[p + 3];
        float2 f0 = unpack_bf16x2(T[(size_t)s0 * 32 + l]);
        float2 f1 = unpack_bf16x2(T[(size_t)s1 * 32 + l]);
        float2 f2 = unpack_bf16x2(T[(size_t)s2 * 32 + l]);
        float2 f3 = unpack_bf16x2(T[(size_t)s3 * 32 + l]);
        ax0 += f0.x; ay0 += f0.y;
        ax1 += f1.x; ay1 += f1.y;
        ax2 += f2.x; ay2 += f2.y;
        ax3 += f3.x; ay3 += f3.y;
    }
    for (; p < end; ++p) {
        float2 f = unpack_bf16x2(T[(size_t)csr_src[p] * 32 + l]);
        ax1 += f.x; ay1 += f.y;
    }
    float2 bb = ((const float2*)b2)[l];
    float vx = ((ax0 + ax1) + (ax2 + ax3)) * dn + bb.x;
    float vy = ((ay0 + ay1) + (ay2 + ay3)) * dn + bb.y;
    float m = fmaxf(vx, vy);
#pragma unroll
    for (int off = 16; off > 0; off >>= 1) m = fmaxf(m, __shfl_xor(m, off, 64));
    float ex = __expf(vx - m) + __expf(vy - m);
    float ssum = ex;
#pragma unroll
    for (int off = 16; off > 0; off >>= 1) ssum += __shfl_xor(ssum, off, 64);
    float lse = m + __logf(ssum);
    float2 o = {vx - lse, vy - lse};
    ((float2*)out)[(size_t)node * 32 + l] = o;
}

extern "C" void kernel_launch(void* const* d_in, const int* in_sizes, int n_in,
                              void* d_out, int out_size, void* d_ws, size_t ws_size,
                              hipStream_t stream) {
    const float* x  = (const float*)d_in[0];
    const int*   ei = (const int*)d_in[1];
    const float* W1 = (const float*)d_in[2];
    const float* b1 = (const float*)d_in[3];
    const float* W2 = (const float*)d_in[4];
    const float* b2 = (const float*)d_in[5];
    float* out = (float*)d_out;

    const int N = in_sizes[0] / 128;  // 50000
    const int E = in_sizes[1] / 2;    // 800000
    const int* src = ei;
    const int* dst = ei + E;
    const int NB = (N + 255) / 256;

    char* ws = (char*)d_ws;
    auto alloc = [&](size_t bytes) -> char* {
        char* p = ws;
        ws += (bytes + 255) & ~(size_t)255;
        return p;
    };
    unsigned short* h1  = (unsigned short*)alloc((size_t)N * 128 * 2);  // bf16
    unsigned short* h1a = (unsigned short*)alloc((size_t)N * 128 * 2);  // bf16
    unsigned short* h2  = (unsigned short*)alloc((size_t)N * 64 * 2);   // bf16
    float* dinv     = (float*)alloc((size_t)N * 4);
    // counts_p and cursor_p share one padded region (counts dead before
    // cursor is written in finalize_k).
    int* counts_p   = (int*)alloc(((size_t)N << PAD) * 4);
    int* cursor_p   = counts_p;
    int*   exscan   = (int*)alloc((size_t)N * 4);
    int*   blocksum = (int*)alloc((size_t)NB * 4);
    int*   blockoff = (int*)alloc((size_t)NB * 4);
    int*   offsets  = (int*)alloc((size_t)(N + 1) * 4);
    int*   csr_src  = (int*)alloc((size_t)E * 4);
    unsigned short* W1t = (unsigned short*)alloc(128 * 128 * 2);
    unsigned short* W2t = (unsigned short*)alloc(64 * 128 * 2);

    const int HB = (E + 2047) / 2048;      // 391 hist blocks (x8 ILP)
    const int GB = (N + 63) / 64;          // 782 gemm blocks
    const int FB = (E + 2047) / 2048;      // 391 fill blocks (x8 ILP)
    const int U  = N * 64;                 // h1 packed-uint count
    const int SB = (U + 1023) / 1024;      // scale blocks (x4 ILP)

    hipMemsetAsync(counts_p, 0, ((size_t)N << PAD) * 4, stream);
    convw_k<<<(128 * 128 + 64 * 128 + 255) / 256, 256, 0, stream>>>(W1, W2, W1t, W2t);
    hist_gemm1_k<<<HB + GB, 256, 0, stream>>>(dst, E, counts_p, x, W1t, (uint32*)h1, N, HB);
    partial_scan_k<<<NB, 256, 0, stream>>>(counts_p, N, exscan, blocksum, dinv);
    scan_blocksums_k<<<1, 256, 0, stream>>>(blocksum, NB, blockoff, offsets + N);
    finalize_k<<<NB, 256, 0, stream>>>(exscan, blockoff, N, offsets, cursor_p);
    fill_scale_k<<<FB + SB, 256, 0, stream>>>(src, dst, E, cursor_p, csr_src,
                                              (uint32*)h1, U, dinv, FB, SB);
    agg1_k<<<(N + 3) / 4, 256, 0, stream>>>(h1, offsets, csr_src, dinv, b1, h1a, N);
    mfma_gemm2_k<<<GB, 256, 0, stream>>>(h1a, W2t, dinv, (uint32*)h2, N);
    agg2_k<<<(N + 7) / 8, 256, 0, stream>>>(h2, offsets, csr_src, dinv, b2, out, N);
}

// Round 8
// 226.411 us; speedup vs baseline: 1.7912x; 1.1051x over previous
//
#include <hip/hip_runtime.h>
#include <hip/hip_bf16.h>
#include <math.h>

// ---------------------------------------------------------------------------
// GCN 2-layer forward on MI355X.
//  memset(counts_r) -> convw(W->bf16^T, pair-permuted)
//  -> FUSED [hist(dst) into per-XCD counter replicas w/ L2-local atomics,
//            rank stored per edge  ||  mfma_gemm1 (unscaled bf16 h1)]
//  -> scan (sum 8 replicas -> offsets, dinv, per-(node,xcd) bases)
//  -> FUSED [fill_csr: pos = base[dst][xcd]+rank, NO atomics || h1 *= dinv]
//  -> agg1 (bf16 gather, +b1, relu) -> mfma_gemm2 (*dinv) -> agg2 (log_softmax)
// R7 analysis: device-scope atomics execute memory-side (~32B HBM RMW per op,
// rate pinned at 1.6e10/s independent of ILP/padding). Fix: (a) fill needs no
// atomics given hist ranks; (b) hist counters replicated per physical XCD
// (HW_REG_XCC_ID) + workgroup-scope atomic -> RMW can execute in XCD-local L2.
// Correctness is scope-independent (replica = physical XCD); only speed varies.
// ---------------------------------------------------------------------------

typedef unsigned int uint32;
typedef __attribute__((ext_vector_type(8))) short bf16x8;
typedef __attribute__((ext_vector_type(4))) float f32x4;

__device__ inline unsigned short f2bf_rne(float f) {
    uint32 x = __float_as_uint(f);
    uint32 r = (x + 0x7fffu + ((x >> 16) & 1u)) >> 16;
    return (unsigned short)r;
}
__device__ inline uint32 pack_bf16x2(float a, float b) {
    return (uint32)f2bf_rne(a) | ((uint32)f2bf_rne(b) << 16);
}
__device__ inline float2 unpack_bf16x2(uint32 u) {
    float2 r;
    r.x = __uint_as_float(u << 16);
    r.y = __uint_as_float(u & 0xffff0000u);
    return r;
}
__device__ inline int xcc_id() {
    int x;
    asm volatile("s_getreg_b32 %0, hwreg(HW_REG_XCC_ID, 0, 4)" : "=s"(x));
    return x & 7;
}

// W -> bf16 transposed, pair-permuted: slot (t,m) holds logical column
// 32*(t>>1) + 2*m + (t&1), so acc pairs (t=2u,2u+1) pack to adjacent cols.
__global__ __launch_bounds__(256) void convw_k(const float* __restrict__ W1,
                                               const float* __restrict__ W2,
                                               unsigned short* __restrict__ W1t,
                                               unsigned short* __restrict__ W2t) {
    int idx = blockIdx.x * 256 + threadIdx.x;
    if (idx < 128 * 128) {
        int ns = idx >> 7, k = idx & 127;
        int t = ns >> 4, m = ns & 15;
        int col = 32 * (t >> 1) + 2 * m + (t & 1);
        W1t[idx] = f2bf_rne(W1[k * 128 + col]);
    } else {
        int i2 = idx - 128 * 128;
        if (i2 < 64 * 128) {
            int ns = i2 >> 7, k = i2 & 127;
            int t = ns >> 4, m = ns & 15;
            int col = 32 * (t >> 1) + 2 * m + (t & 1);
            W2t[i2] = f2bf_rne(W2[k * 64 + col]);
        }
    }
}

// FUSED: blocks [0,HB): histogram into per-XCD replica, store rank+xcd/edge.
//        blocks [HB,HB+GB): mfma gemm1 h1 = bf16(x @ W1t) (unscaled).
__global__ __launch_bounds__(256) void hist_gemm1_k(const int* __restrict__ dst, int E,
                                                    int* __restrict__ counts_r, int N,
                                                    uint32* __restrict__ rankx,
                                                    const float* __restrict__ X,
                                                    const unsigned short* __restrict__ Wt,
                                                    uint32* __restrict__ Yu,
                                                    int Nrows, int HB) {
    if ((int)blockIdx.x < HB) {
        const int x = xcc_id();
        int* cr = counts_r + (size_t)x * N;
        const uint32 xb = (uint32)x << 27;
        const int T = HB * 256;
        const int i = blockIdx.x * 256 + threadIdx.x;
#pragma unroll
        for (int j = 0; j < 8; ++j) {
            int e = i + j * T;
            if (e < E) {
                int d = dst[e];
                int r = __hip_atomic_fetch_add(&cr[d], 1, __ATOMIC_RELAXED,
                                               __HIP_MEMORY_SCOPE_WORKGROUP);
                rankx[e] = xb | (uint32)r;
            }
        }
        return;
    }
    constexpr int NCOL = 128;
    constexpr int NT = NCOL / 16;
    const int tid  = threadIdx.x;
    const int wave = tid >> 6;
    const int lane = tid & 63;
    const int m16  = lane & 15;
    const int q    = lane >> 4;
    const int r0   = ((int)blockIdx.x - HB) * 64 + wave * 16;

    int arow = r0 + m16;
    if (arow >= Nrows) arow = Nrows - 1;

    bf16x8 afrag[4];
#pragma unroll
    for (int kb = 0; kb < 4; ++kb) {
        const float* p = &X[(size_t)arow * 128 + kb * 32 + q * 8];
        float4 u0 = *(const float4*)p;
        float4 u1 = *(const float4*)(p + 4);
        bf16x8 a;
        a[0] = (short)f2bf_rne(u0.x); a[1] = (short)f2bf_rne(u0.y);
        a[2] = (short)f2bf_rne(u0.z); a[3] = (short)f2bf_rne(u0.w);
        a[4] = (short)f2bf_rne(u1.x); a[5] = (short)f2bf_rne(u1.y);
        a[6] = (short)f2bf_rne(u1.z); a[7] = (short)f2bf_rne(u1.w);
        afrag[kb] = a;
    }

    f32x4 acc[NT];
#pragma unroll
    for (int t = 0; t < NT; ++t) acc[t] = (f32x4){0.f, 0.f, 0.f, 0.f};
#pragma unroll
    for (int t = 0; t < NT; ++t) {
        const unsigned short* Bp = &Wt[(size_t)(t * 16 + m16) * 128 + q * 8];
#pragma unroll
        for (int kb = 0; kb < 4; ++kb) {
            bf16x8 bfrag = *(const bf16x8*)&Bp[kb * 32];
            acc[t] = __builtin_amdgcn_mfma_f32_16x16x32_bf16(afrag[kb], bfrag, acc[t], 0, 0, 0);
        }
    }
#pragma unroll
    for (int i = 0; i < 4; ++i) {
        int row = r0 + q * 4 + i;
        if (row < Nrows) {
#pragma unroll
            for (int u = 0; u < NT / 2; ++u)
                Yu[(size_t)row * (NCOL / 2) + u * 16 + m16] =
                    pack_bf16x2(acc[2 * u][i], acc[2 * u + 1][i]);
        }
    }
}

// Per-node total over 8 replicas -> block-local exscan + dinv + blocksum.
__global__ __launch_bounds__(256) void partial_scan_k(const int* __restrict__ counts_r, int N,
                                                      int* __restrict__ exscan,
                                                      int* __restrict__ blocksum,
                                                      float* __restrict__ dinv) {
    __shared__ int sd[256];
    const int tid = threadIdx.x;
    const int gid = blockIdx.x * 256 + tid;
    int v = 0;
    if (gid < N) {
#pragma unroll
        for (int x = 0; x < 8; ++x) v += counts_r[(size_t)x * N + gid];
    }
    sd[tid] = v;
    __syncthreads();
    for (int off = 1; off < 256; off <<= 1) {
        int t = (tid >= off) ? sd[tid - off] : 0;
        __syncthreads();
        sd[tid] += t;
        __syncthreads();
    }
    if (gid < N) {
        exscan[gid] = sd[tid] - v;
        dinv[gid]   = rsqrtf((float)(v + 1));
    }
    if (tid == 255) blocksum[blockIdx.x] = sd[255];
}

__global__ __launch_bounds__(256) void scan_blocksums_k(const int* __restrict__ blocksum, int NB,
                                                        int* __restrict__ blockoff,
                                                        int* __restrict__ offsets_last) {
    __shared__ int sd[256];
    const int tid = threadIdx.x;
    int v = (tid < NB) ? blocksum[tid] : 0;
    sd[tid] = v;
    __syncthreads();
    for (int off = 1; off < 256; off <<= 1) {
        int t = (tid >= off) ? sd[tid - off] : 0;
        __syncthreads();
        sd[tid] += t;
        __syncthreads();
    }
    if (tid < NB) blockoff[tid] = sd[tid] - v;
    if (tid == 255) *offsets_last = sd[255];
}

// offsets[n] + per-(node,xcd) bases: base[n*8+x] = offsets[n] + prefix(counts).
__global__ __launch_bounds__(256) void finalize_k(const int* __restrict__ exscan,
                                                  const int* __restrict__ blockoff,
                                                  const int* __restrict__ counts_r, int N,
                                                  int* __restrict__ offsets,
                                                  int* __restrict__ base) {
    const int gid = blockIdx.x * 256 + threadIdx.x;
    if (gid < N) {
        int o = blockoff[blockIdx.x] + exscan[gid];
        offsets[gid] = o;
        int running = o;
#pragma unroll
        for (int x = 0; x < 8; ++x) {
            base[(size_t)gid * 8 + x] = running;
            running += counts_r[(size_t)x * N + gid];
        }
    }
}

// FUSED: blocks [0,FB): fill CSR via pos = base[dst*8+xcd] + rank (NO atomics).
//        blocks [FB,FB+SB): scale h1 (packed bf16x2) by dinv[row], x4 ILP.
__global__ __launch_bounds__(256) void fill_scale_k(const int* __restrict__ src,
                                                    const int* __restrict__ dst, int E,
                                                    const uint32* __restrict__ rankx,
                                                    const int* __restrict__ base,
                                                    int* __restrict__ csr_src,
                                                    uint32* __restrict__ H, int U,
                                                    const float* __restrict__ dinv,
                                                    int FB, int SB) {
    if ((int)blockIdx.x < FB) {
        const int T = FB * 256;
        const int i = blockIdx.x * 256 + threadIdx.x;
#pragma unroll
        for (int j = 0; j < 8; ++j) {
            int e = i + j * T;
            if (e < E) {
                int d = dst[e];
                uint32 rx = rankx[e];
                int pos = base[(size_t)d * 8 + (rx >> 27)] + (int)(rx & 0x07ffffffu);
                csr_src[pos] = src[e];
            }
        }
        return;
    }
    const int T2 = SB * 256;
    const int i = ((int)blockIdx.x - FB) * 256 + threadIdx.x;
#pragma unroll
    for (int j = 0; j < 4; ++j) {
        int idx = i + j * T2;
        if (idx < U) {
            float dn = dinv[idx >> 6];
            float2 f = unpack_bf16x2(H[idx]);
            H[idx] = pack_bf16x2(f.x * dn, f.y * dn);
        }
    }
}

// MFMA GEMM2: h2[r,:] = bf16( (h1a[r,:128] @ W2t) * dinv[r] ), pair-packed stores.
__global__ __launch_bounds__(256) void mfma_gemm2_k(const unsigned short* __restrict__ X,
                                                    const unsigned short* __restrict__ Wt,
                                                    const float* __restrict__ dinv,
                                                    uint32* __restrict__ Yu, int Nrows) {
    constexpr int NCOL = 64;
    constexpr int NT = NCOL / 16;
    const int tid  = threadIdx.x;
    const int wave = tid >> 6;
    const int lane = tid & 63;
    const int m16  = lane & 15;
    const int q    = lane >> 4;
    const int r0   = blockIdx.x * 64 + wave * 16;

    int arow = r0 + m16;
    if (arow >= Nrows) arow = Nrows - 1;

    bf16x8 afrag[4];
#pragma unroll
    for (int kb = 0; kb < 4; ++kb)
        afrag[kb] = *(const bf16x8*)&X[(size_t)arow * 128 + kb * 32 + q * 8];

    f32x4 acc[NT];
#pragma unroll
    for (int t = 0; t < NT; ++t) acc[t] = (f32x4){0.f, 0.f, 0.f, 0.f};
#pragma unroll
    for (int t = 0; t < NT; ++t) {
        const unsigned short* Bp = &Wt[(size_t)(t * 16 + m16) * 128 + q * 8];
#pragma unroll
        for (int kb = 0; kb < 4; ++kb) {
            bf16x8 bfrag = *(const bf16x8*)&Bp[kb * 32];
            acc[t] = __builtin_amdgcn_mfma_f32_16x16x32_bf16(afrag[kb], bfrag, acc[t], 0, 0, 0);
        }
    }
#pragma unroll
    for (int i = 0; i < 4; ++i) {
        int row = r0 + q * 4 + i;
        if (row < Nrows) {
            float dn = dinv[row];
#pragma unroll
            for (int u = 0; u < NT / 2; ++u)
                Yu[(size_t)row * (NCOL / 2) + u * 16 + m16] =
                    pack_bf16x2(acc[2 * u][i] * dn, acc[2 * u + 1][i] * dn);
        }
    }
}

// Layer-1 aggregation: 64 lanes/node, 2 ch/lane, 4 nodes/block, x4 unroll.
__global__ __launch_bounds__(256) void agg1_k(const unsigned short* __restrict__ hs,
                                              const int* __restrict__ offsets,
                                              const int* __restrict__ csr_src,
                                              const float* __restrict__ dinv,
                                              const float* __restrict__ b1,
                                              unsigned short* __restrict__ out, int N) {
    const int tid  = threadIdx.x;
    const int node = blockIdx.x * 4 + (tid >> 6);
    const int lane = tid & 63;
    if (node >= N) return;
    const uint32* T = (const uint32*)hs;
    const int start = offsets[node];
    const int end   = offsets[node + 1];
    const float dn  = dinv[node];
    float2 self = unpack_bf16x2(T[(size_t)node * 64 + lane]);
    float ax0 = self.x, ay0 = self.y;
    float ax1 = 0.f, ay1 = 0.f, ax2 = 0.f, ay2 = 0.f, ax3 = 0.f, ay3 = 0.f;
    int p = start;
    for (; p + 3 < end; p += 4) {
        int s0 = csr_src[p];
        int s1 = csr_src[p + 1];
        int s2 = csr_src[p + 2];
        int s3 = csr_src[p + 3];
        float2 f0 = unpack_bf16x2(T[(size_t)s0 * 64 + lane]);
        float2 f1 = unpack_bf16x2(T[(size_t)s1 * 64 + lane]);
        float2 f2 = unpack_bf16x2(T[(size_t)s2 * 64 + lane]);
        float2 f3 = unpack_bf16x2(T[(size_t)s3 * 64 + lane]);
        ax0 += f0.x; ay0 += f0.y;
        ax1 += f1.x; ay1 += f1.y;
        ax2 += f2.x; ay2 += f2.y;
        ax3 += f3.x; ay3 += f3.y;
    }
    for (; p < end; ++p) {
        float2 f = unpack_bf16x2(T[(size_t)csr_src[p] * 64 + lane]);
        ax1 += f.x; ay1 += f.y;
    }
    float2 bb = ((const float2*)b1)[lane];
    float vx = ((ax0 + ax1) + (ax2 + ax3)) * dn + bb.x;
    float vy = ((ay0 + ay1) + (ay2 + ay3)) * dn + bb.y;
    vx = vx > 0.f ? vx : 0.f;
    vy = vy > 0.f ? vy : 0.f;
    ((uint32*)out)[(size_t)node * 64 + lane] = pack_bf16x2(vx, vy);
}

// Layer-2 aggregation + bias + log_softmax. 32 lanes/node, 8 nodes/block.
__global__ __launch_bounds__(256) void agg2_k(const unsigned short* __restrict__ hs,
                                              const int* __restrict__ offsets,
                                              const int* __restrict__ csr_src,
                                              const float* __restrict__ dinv,
                                              const float* __restrict__ b2,
                                              float* __restrict__ out, int N) {
    const int tid  = threadIdx.x;
    const int node = blockIdx.x * 8 + (tid >> 5);
    const int l    = tid & 31;
    if (node >= N) return;
    const uint32* T = (const uint32*)hs;
    const int start = offsets[node];
    const int end   = offsets[node + 1];
    const float dn  = dinv[node];
    float2 self = unpack_bf16x2(T[(size_t)node * 32 + l]);
    float ax0 = self.x, ay0 = self.y;
    float ax1 = 0.f, ay1 = 0.f, ax2 = 0.f, ay2 = 0.f, ax3 = 0.f, ay3 = 0.f;
    int p = start;
    for (; p + 3 < end; p += 4) {
        int s0 = csr_src[p];
        int s1 = csr_src[p + 1];
        int s2 = csr_src[p + 2];
        int s3 = csr_src[p + 3];
        float2 f0 = unpack_bf16x2(T[(size_t)s0 * 32 + l]);
        float2 f1 = unpack_bf16x2(T[(size_t)s1 * 32 + l]);
        float2 f2 = unpack_bf16x2(T[(size_t)s2 * 32 + l]);
        float2 f3 = unpack_bf16x2(T[(size_t)s3 * 32 + l]);
        ax0 += f0.x; ay0 += f0.y;
        ax1 += f1.x; ay1 += f1.y;
        ax2 += f2.x; ay2 += f2.y;
        ax3 += f3.x; ay3 += f3.y;
    }
    for (; p < end; ++p) {
        float2 f = unpack_bf16x2(T[(size_t)csr_src[p] * 32 + l]);
        ax1 += f.x; ay1 += f.y;
    }
    float2 bb = ((const float2*)b2)[l];
    float vx = ((ax0 + ax1) + (ax2 + ax3)) * dn + bb.x;
    float vy = ((ay0 + ay1) + (ay2 + ay3)) * dn + bb.y;
    float m = fmaxf(vx, vy);
#pragma unroll
    for (int off = 16; off > 0; off >>= 1) m = fmaxf(m, __shfl_xor(m, off, 64));
    float ex = __expf(vx - m) + __expf(vy - m);
    float ssum = ex;
#pragma unroll
    for (int off = 16; off > 0; off >>= 1) ssum += __shfl_xor(ssum, off, 64);
    float lse = m + __logf(ssum);
    float2 o = {vx - lse, vy - lse};
    ((float2*)out)[(size_t)node * 32 + l] = o;
}

extern "C" void kernel_launch(void* const* d_in, const int* in_sizes, int n_in,
                              void* d_out, int out_size, void* d_ws, size_t ws_size,
                              hipStream_t stream) {
    const float* x  = (const float*)d_in[0];
    const int*   ei = (const int*)d_in[1];
    const float* W1 = (const float*)d_in[2];
    const float* b1 = (const float*)d_in[3];
    const float* W2 = (const float*)d_in[4];
    const float* b2 = (const float*)d_in[5];
    float* out = (float*)d_out;

    const int N = in_sizes[0] / 128;  // 50000
    const int E = in_sizes[1] / 2;    // 800000
    const int* src = ei;
    const int* dst = ei + E;
    const int NB = (N + 255) / 256;

    char* ws = (char*)d_ws;
    auto alloc = [&](size_t bytes) -> char* {
        char* p = ws;
        ws += (bytes + 255) & ~(size_t)255;
        return p;
    };
    unsigned short* h1  = (unsigned short*)alloc((size_t)N * 128 * 2);  // bf16
    unsigned short* h1a = (unsigned short*)alloc((size_t)N * 128 * 2);  // bf16
    unsigned short* h2  = (unsigned short*)alloc((size_t)N * 64 * 2);   // bf16
    float* dinv     = (float*)alloc((size_t)N * 4);
    int*   counts_r = (int*)alloc((size_t)8 * N * 4);   // per-XCD replicas
    uint32* rankx   = (uint32*)alloc((size_t)E * 4);    // (xcd<<27)|rank per edge
    int*   base     = (int*)alloc((size_t)N * 8 * 4);   // per-(node,xcd) start
    int*   exscan   = (int*)alloc((size_t)N * 4);
    int*   blocksum = (int*)alloc((size_t)NB * 4);
    int*   blockoff = (int*)alloc((size_t)NB * 4);
    int*   offsets  = (int*)alloc((size_t)(N + 1) * 4);
    int*   csr_src  = (int*)alloc((size_t)E * 4);
    unsigned short* W1t = (unsigned short*)alloc(128 * 128 * 2);
    unsigned short* W2t = (unsigned short*)alloc(64 * 128 * 2);

    const int HB = (E + 2047) / 2048;      // 391 hist blocks (x8 ILP)
    const int GB = (N + 63) / 64;          // 782 gemm blocks
    const int FB = (E + 2047) / 2048;      // 391 fill blocks (x8 ILP)
    const int U  = N * 64;                 // h1 packed-uint count
    const int SB = (U + 1023) / 1024;      // scale blocks (x4 ILP)

    hipMemsetAsync(counts_r, 0, (size_t)8 * N * 4, stream);
    convw_k<<<(128 * 128 + 64 * 128 + 255) / 256, 256, 0, stream>>>(W1, W2, W1t, W2t);
    hist_gemm1_k<<<HB + GB, 256, 0, stream>>>(dst, E, counts_r, N, rankx,
                                              x, W1t, (uint32*)h1, N, HB);
    partial_scan_k<<<NB, 256, 0, stream>>>(counts_r, N, exscan, blocksum, dinv);
    scan_blocksums_k<<<1, 256, 0, stream>>>(blocksum, NB, blockoff, offsets + N);
    finalize_k<<<NB, 256, 0, stream>>>(exscan, blockoff, counts_r, N, offsets, base);
    fill_scale_k<<<FB + SB, 256, 0, stream>>>(src, dst, E, rankx, base, csr_src,
                                              (uint32*)h1, U, dinv, FB, SB);
    agg1_k<<<(N + 3) / 4, 256, 0, stream>>>(h1, offsets, csr_src, dinv, b1, h1a, N);
    mfma_gemm2_k<<<GB, 256, 0, stream>>>(h1a, W2t, dinv, (uint32*)h2, N);
    agg2_k<<<(N + 7) / 8, 256, 0, stream>>>(h2, offsets, csr_src, dinv, b2, out, N);
}